// Round 1
// baseline (7560.138 us; speedup 1.0000x reference)
//
#include <hip/hip_runtime.h>
#include <math.h>

#define NPIX 4096
#define CH   256

// ---- ws float offsets ----
#define OFF_XT   0u          // [2][4096][256] f32
#define OFF_Y    2097152u    // [2][4096][256] f32 (reused as xnew after v-agg)
#define OFF_E    4194304u    // [2][4096][256] f32
#define OFF_SQ   6291456u    // [2][4096] f32
#define OFF_PART 6299648u    // [128][512] f32 BN partials
#define OFF_BNSS 6365184u    // [512] f32 (scale[256], shift[256])
#define OFF_HG   6365696u    // uint32 [2][4096][128] bitmask
#define OFF_XA   7414272u    // [2][256][64][64] f32 (NCHW, post BN+SiLU)
#define OFF_W2   9511424u    // [256*9][256] f32 reordered conv weights
#define OFF_XDT  10101248u   // [2][1024][256] f32 (px-major conv output)
// end: 10625536 floats = 42.5 MB

// ---------- transpose x[b][c][n] -> xt[b][n][c] ----------
__global__ void k_transpose(const float* __restrict__ x, float* __restrict__ xt) {
  __shared__ float tile[32][33];
  const int b = blockIdx.z;
  const int n0 = blockIdx.x * 32, c0 = blockIdx.y * 32;
  const int tx = threadIdx.x, ty = threadIdx.y;
  const float* xb = x + (size_t)b * CH * NPIX;
  float* xtb = xt + (size_t)b * NPIX * CH;
#pragma unroll
  for (int k = 0; k < 4; ++k)
    tile[ty + k * 8][tx] = xb[(c0 + ty + k * 8) * NPIX + n0 + tx];
  __syncthreads();
#pragma unroll
  for (int k = 0; k < 4; ++k)
    xtb[(n0 + ty + k * 8) * CH + c0 + tx] = tile[tx][ty + k * 8];
}

// ---------- row squared norms ----------
__global__ void k_sq(const float* __restrict__ xt, float* __restrict__ sq) {
  const int row = blockIdx.x;  // 0..8191
  const int t = threadIdx.x;   // 64
  const float4 v = reinterpret_cast<const float4*>(xt + (size_t)row * CH)[t];
  float s = v.x * v.x + v.y * v.y + v.z * v.z + v.w * v.w;
#pragma unroll
  for (int off = 32; off; off >>= 1) s += __shfl_down(s, off);
  if (t == 0) sq[row] = s;
}

// ---------- Gram GEMM (fp32) with fused threshold -> bitmask ----------
__global__ __launch_bounds__(256) void k_gram(const float* __restrict__ xt,
                                              const float* __restrict__ sq,
                                              unsigned* __restrict__ hgbit) {
  __shared__ float As[16][128];
  __shared__ float Bs[16][128];
  __shared__ unsigned char bits[128][16];
  const int b = blockIdx.z;
  const int i0 = blockIdx.y * 128, j0 = blockIdx.x * 128;
  const int t = threadIdx.x;
  const int tx = t & 15, ty = t >> 4;
  const float* base = xt + (size_t)b * NPIX * CH;
  float acc[8][8];
#pragma unroll
  for (int r = 0; r < 8; ++r)
#pragma unroll
    for (int s = 0; s < 8; ++s) acc[r][s] = 0.f;

  for (int k0 = 0; k0 < CH; k0 += 16) {
#pragma unroll
    for (int q = 0; q < 2; ++q) {
      const int fi = t * 2 + q;
      const int r = fi >> 2, kq = fi & 3;
      float4 av = *reinterpret_cast<const float4*>(base + (size_t)(i0 + r) * CH + k0 + kq * 4);
      As[kq * 4 + 0][r] = av.x; As[kq * 4 + 1][r] = av.y;
      As[kq * 4 + 2][r] = av.z; As[kq * 4 + 3][r] = av.w;
      float4 bv = *reinterpret_cast<const float4*>(base + (size_t)(j0 + r) * CH + k0 + kq * 4);
      Bs[kq * 4 + 0][r] = bv.x; Bs[kq * 4 + 1][r] = bv.y;
      Bs[kq * 4 + 2][r] = bv.z; Bs[kq * 4 + 3][r] = bv.w;
    }
    __syncthreads();
#pragma unroll
    for (int kk = 0; kk < 16; ++kk) {
      float a[8], bb[8];
      *(float4*)&a[0]  = *(const float4*)&As[kk][ty * 8];
      *(float4*)&a[4]  = *(const float4*)&As[kk][ty * 8 + 4];
      *(float4*)&bb[0] = *(const float4*)&Bs[kk][tx * 8];
      *(float4*)&bb[4] = *(const float4*)&Bs[kk][tx * 8 + 4];
#pragma unroll
      for (int r = 0; r < 8; ++r)
#pragma unroll
        for (int s = 0; s < 8; ++s) acc[r][s] += a[r] * bb[s];
    }
    __syncthreads();
  }
  float sqi[8], sqj[8];
#pragma unroll
  for (int r = 0; r < 8; ++r) sqi[r] = sq[b * NPIX + i0 + ty * 8 + r];
#pragma unroll
  for (int s = 0; s < 8; ++s) sqj[s] = sq[b * NPIX + j0 + tx * 8 + s];
#pragma unroll
  for (int r = 0; r < 8; ++r) {
    unsigned m = 0;
#pragma unroll
    for (int s = 0; s < 8; ++s) {
      const float d2 = sqi[r] + sqj[s] - 2.f * acc[r][s];
      m |= (d2 < 100.f) ? (1u << s) : 0u;
    }
    bits[ty * 8 + r][tx] = (unsigned char)m;
  }
  __syncthreads();
#pragma unroll
  for (int q = 0; q < 2; ++q) {
    const int w = t + q * 256;              // 0..511
    const int row = w >> 2, wc = w & 3;
    const unsigned word = (unsigned)bits[row][wc * 4] |
                          ((unsigned)bits[row][wc * 4 + 1] << 8) |
                          ((unsigned)bits[row][wc * 4 + 2] << 16) |
                          ((unsigned)bits[row][wc * 4 + 3] << 24);
    hgbit[(size_t)(b * NPIX + i0 + row) * 128 + (j0 >> 5) + wc] = word;
  }
}

// ---------- generic 64x64 GEMM: C = A(MxK) * B(NxK)^T + bias ----------
__global__ __launch_bounds__(256) void k_gemm_nt64(const float* __restrict__ A,
                                                   const float* __restrict__ B,
                                                   float* __restrict__ C,
                                                   const float* __restrict__ bias,
                                                   int M, int N, int K, int biasRow,
                                                   int aStride, int bStride, int cStride) {
  A += (size_t)blockIdx.z * aStride;
  B += (size_t)blockIdx.z * bStride;
  C += (size_t)blockIdx.z * cStride;
  __shared__ float As[16][64];
  __shared__ float Bs[16][64];
  const int m0 = blockIdx.y * 64, n0 = blockIdx.x * 64;
  const int t = threadIdx.x, tx = t & 15, ty = t >> 4;
  float acc[4][4];
#pragma unroll
  for (int r = 0; r < 4; ++r)
#pragma unroll
    for (int s = 0; s < 4; ++s) acc[r][s] = 0.f;

  for (int k0 = 0; k0 < K; k0 += 16) {
    const int r = t >> 2, kq = t & 3;
    float4 av = *reinterpret_cast<const float4*>(A + (size_t)(m0 + r) * K + k0 + kq * 4);
    As[kq * 4 + 0][r] = av.x; As[kq * 4 + 1][r] = av.y;
    As[kq * 4 + 2][r] = av.z; As[kq * 4 + 3][r] = av.w;
    float4 bv = *reinterpret_cast<const float4*>(B + (size_t)(n0 + r) * K + k0 + kq * 4);
    Bs[kq * 4 + 0][r] = bv.x; Bs[kq * 4 + 1][r] = bv.y;
    Bs[kq * 4 + 2][r] = bv.z; Bs[kq * 4 + 3][r] = bv.w;
    __syncthreads();
#pragma unroll
    for (int kk = 0; kk < 16; ++kk) {
      float4 a4 = *(const float4*)&As[kk][ty * 4];
      float4 b4 = *(const float4*)&Bs[kk][tx * 4];
      const float a[4] = {a4.x, a4.y, a4.z, a4.w};
      const float bb[4] = {b4.x, b4.y, b4.z, b4.w};
#pragma unroll
      for (int r = 0; r < 4; ++r)
#pragma unroll
        for (int s = 0; s < 4; ++s) acc[r][s] += a[r] * bb[s];
    }
    __syncthreads();
  }
#pragma unroll
  for (int r = 0; r < 4; ++r) {
    float4 v;
    const int row = m0 + ty * 4 + r;
    float* cp = C + (size_t)row * N + n0 + tx * 4;
    if (biasRow) {
      const float bv = bias[row];
      v.x = acc[r][0] + bv; v.y = acc[r][1] + bv; v.z = acc[r][2] + bv; v.w = acc[r][3] + bv;
    } else {
      v.x = acc[r][0] + bias[n0 + tx * 4 + 0];
      v.y = acc[r][1] + bias[n0 + tx * 4 + 1];
      v.z = acc[r][2] + bias[n0 + tx * 4 + 2];
      v.w = acc[r][3] + bias[n0 + tx * 4 + 3];
    }
    *(float4*)cp = v;
  }
}

// ---------- sparse mean-aggregation over bitmask rows ----------
__global__ void k_agg(const unsigned* __restrict__ hgbit, const float* __restrict__ src,
                      const float* __restrict__ resid, float* __restrict__ dst) {
  const int row = blockIdx.x;  // b*4096 + i
  const int b = row >> 12;
  const int t = threadIdx.x;   // 256
  __shared__ unsigned wrd[128];
  if (t < 128) wrd[t] = hgbit[(size_t)row * 128 + t];
  __syncthreads();
  float acc = 0.f;
  int deg = 0;
  const float* sb = src + (size_t)b * NPIX * CH;
  for (int w = 0; w < 128; ++w) {
    unsigned u = wrd[w];
    deg += __popc(u);
    while (u) {
      const int j = (w << 5) + __ffs(u) - 1;
      u &= u - 1;
      acc += sb[(size_t)j * CH + t];
    }
  }
  float r = acc / (float)deg;
  if (resid) r += resid[(size_t)row * CH + t];
  dst[(size_t)row * CH + t] = r;
}

// ---------- BN statistics: per-block partial sums ----------
__global__ void k_bnstat(const float* __restrict__ xn, float* __restrict__ part) {
  const int t = threadIdx.x, blk = blockIdx.x;  // 128 blocks x 64 rows
  float s = 0.f, ss = 0.f;
  const float* p = xn + (size_t)blk * 64 * CH;
  for (int r = 0; r < 64; ++r) {
    const float v = p[r * CH + t];
    s += v; ss += v * v;
  }
  part[blk * 512 + t] = s;
  part[blk * 512 + 256 + t] = ss;
}

__global__ void k_bnfin(const float* __restrict__ part, const float* __restrict__ gamma,
                        const float* __restrict__ beta, float* __restrict__ bnss) {
  const int t = threadIdx.x;  // 256
  float s = 0.f, ss = 0.f;
  for (int i = 0; i < 128; ++i) { s += part[i * 512 + t]; ss += part[i * 512 + 256 + t]; }
  const float mean = s * (1.f / 8192.f);
  const float var = ss * (1.f / 8192.f) - mean * mean;
  const float inv = rsqrtf(var + 1e-5f);
  const float sc = gamma[t] * inv;
  bnss[t] = sc;
  bnss[256 + t] = beta[t] - mean * sc;
}

// ---------- BN apply + SiLU + transpose [b][n][c] -> [b][c][n] ----------
__global__ void k_bnapply(const float* __restrict__ xn, const float* __restrict__ bnss,
                          float* __restrict__ xa) {
  __shared__ float tile[32][33];
  const int b = blockIdx.z;
  const int n0 = blockIdx.x * 32, c0 = blockIdx.y * 32;
  const int tx = threadIdx.x, ty = threadIdx.y;
  const float* xb = xn + (size_t)b * NPIX * CH;
  float* ob = xa + (size_t)b * CH * NPIX;
#pragma unroll
  for (int k = 0; k < 4; ++k)
    tile[ty + k * 8][tx] = xb[(n0 + ty + k * 8) * CH + c0 + tx];
  __syncthreads();
#pragma unroll
  for (int k = 0; k < 4; ++k) {
    const int c = c0 + ty + k * 8;
    const float u = tile[tx][ty + k * 8] * bnss[c] + bnss[256 + c];
    const float sil = u / (1.f + expf(-u));
    ob[(size_t)c * NPIX + n0 + tx] = sil;
  }
}

// ---------- reorder conv weights [oc][c][kh][kw] -> [c*9][oc] ----------
__global__ void k_w2(const float* __restrict__ w, float* __restrict__ w2) {
  const int i = blockIdx.x * 256 + threadIdx.x;  // 589824
  const int oc = i / (CH * 9);
  const int rem = i % (CH * 9);  // c*9 + kh*3 + kw
  w2[(size_t)rem * 256 + oc] = w[i];
}

// ---------- 3x3 stride-2 conv (pad bottom/right), writes xdT[b][px][oc] ----------
__global__ __launch_bounds__(256) void k_conv(const float* __restrict__ xa,
                                              const float* __restrict__ w2,
                                              const float* __restrict__ bias,
                                              float* __restrict__ xdT) {
  __shared__ float p_s[4 * 17 * 19];  // [c][17][19] padded rows
  const int b = blockIdx.z;
  const int ocg = blockIdx.y;  // 8 -> 32 oc each
  const int sp = blockIdx.x;   // 16 -> 8x8 px tiles
  const int oh0 = (sp >> 2) * 8, ow0 = (sp & 3) * 8;
  const int t = threadIdx.x;
  const int w = t >> 6, lane = t & 63;
  const int ph = lane >> 3, pw = lane & 7;
  const int ocb = __builtin_amdgcn_readfirstlane(ocg * 32 + w * 8);
  float acc[8];
#pragma unroll
  for (int o = 0; o < 8; ++o) acc[o] = 0.f;
  const float* xb = xa + (size_t)b * CH * NPIX;

  for (int c4 = 0; c4 < 64; ++c4) {
    __syncthreads();
    for (int e = t; e < 4 * 289; e += 256) {
      const int c = e / 289, rem = e % 289, r = rem / 17, col = rem % 17;
      const int ih = oh0 * 2 + r, iw = ow0 * 2 + col;
      const float v = (ih < 64 && iw < 64) ? xb[((c4 * 4 + c) * 64 + ih) * 64 + iw] : 0.f;
      p_s[c * 323 + r * 19 + col] = v;
    }
    __syncthreads();
#pragma unroll
    for (int cl = 0; cl < 4; ++cl) {
      const int cg = c4 * 4 + cl;
#pragma unroll
      for (int kh = 0; kh < 3; ++kh) {
#pragma unroll
        for (int kw = 0; kw < 3; ++kw) {
          const float in = p_s[cl * 323 + (2 * ph + kh) * 19 + 2 * pw + kw];
          const float* wv = w2 + (size_t)(cg * 9 + kh * 3 + kw) * 256 + ocb;
#pragma unroll
          for (int o = 0; o < 8; ++o) acc[o] += in * wv[o];
        }
      }
    }
  }
  const int px = (oh0 + ph) * 32 + (ow0 + pw);
  float* out = xdT + ((size_t)b * 1024 + px) * 256 + ocb;
  float4 v0, v1;
  v0.x = acc[0] + bias[ocb + 0]; v0.y = acc[1] + bias[ocb + 1];
  v0.z = acc[2] + bias[ocb + 2]; v0.w = acc[3] + bias[ocb + 3];
  v1.x = acc[4] + bias[ocb + 4]; v1.y = acc[5] + bias[ocb + 5];
  v1.z = acc[6] + bias[ocb + 6]; v1.w = acc[7] + bias[ocb + 7];
  *(float4*)out = v0;
  *(float4*)(out + 4) = v1;
}

extern "C" void kernel_launch(void* const* d_in, const int* in_sizes, int n_in,
                              void* d_out, int out_size, void* d_ws, size_t ws_size,
                              hipStream_t stream) {
  const float* x     = (const float*)d_in[0];
  const float* fc_w  = (const float*)d_in[1];
  const float* fc_b  = (const float*)d_in[2];
  const float* gamma = (const float*)d_in[3];
  const float* beta  = (const float*)d_in[4];
  const float* dw    = (const float*)d_in[5];
  const float* db    = (const float*)d_in[6];
  const float* ow    = (const float*)d_in[7];
  const float* ob    = (const float*)d_in[8];

  float* ws   = (float*)d_ws;
  float* xt   = ws + OFF_XT;
  float* y    = ws + OFF_Y;     // later reused as xnew
  float* E    = ws + OFF_E;
  float* sqv  = ws + OFF_SQ;
  float* part = ws + OFF_PART;
  float* bnss = ws + OFF_BNSS;
  unsigned* hg = (unsigned*)(ws + OFF_HG);
  float* xa   = ws + OFF_XA;
  float* w2   = ws + OFF_W2;
  float* xdT  = ws + OFF_XDT;
  float* out  = (float*)d_out;

  k_transpose<<<dim3(128, 8, 2), dim3(32, 8), 0, stream>>>(x, xt);
  k_sq<<<8192, 64, 0, stream>>>(xt, sqv);
  k_w2<<<2304, 256, 0, stream>>>(dw, w2);
  k_gram<<<dim3(32, 32, 2), 256, 0, stream>>>(xt, sqv, hg);
  // y = xf @ fc_w^T + fc_b : M=8192 N=256 K=256
  k_gemm_nt64<<<dim3(4, 128, 1), 256, 0, stream>>>(xt, fc_w, y, fc_b,
                                                   8192, 256, 256, 0, 0, 0, 0);
  k_agg<<<8192, 256, 0, stream>>>(hg, y, nullptr, E);   // vertex -> edge
  k_agg<<<8192, 256, 0, stream>>>(hg, E, xt, y);        // edge -> vertex + residual
  k_bnstat<<<128, 256, 0, stream>>>(y, part);
  k_bnfin<<<1, 256, 0, stream>>>(part, gamma, beta, bnss);
  k_bnapply<<<dim3(128, 8, 2), dim3(32, 8), 0, stream>>>(y, bnss, xa);
  k_conv<<<dim3(16, 8, 2), 256, 0, stream>>>(xa, w2, db, xdT);
  // out = out_w @ xdT^T + out_b : per batch M=512 N=1024 K=256 (row bias)
  k_gemm_nt64<<<dim3(16, 8, 2), 256, 0, stream>>>(ow, xdT, out, ob,
                                                  512, 1024, 256, 1,
                                                  0, 1024 * 256, 512 * 1024);
}

// Round 2
// 961.800 us; speedup vs baseline: 7.8604x; 7.8604x over previous
//
#include <hip/hip_runtime.h>
#include <math.h>

#define NPIX 4096
#define CH   256

// ---- ws float offsets ----
#define OFF_XT   0u          // [2][4096][256] f32
#define OFF_Y    2097152u    // [2][4096][256] f32 (reused as xnew after v-agg)
#define OFF_E    4194304u    // [2][4096][256] f32 (reused as conv partials)
#define OFF_SQ   6291456u    // [2][4096] f32
#define OFF_PART 6299648u    // [128][512] f32 BN partials (also hosts colsum scratch earlier)
#define OFF_SPY  6299648u    // [2][16][256] colsum partials of y (dead before bnstat)
#define OFF_SY   6307840u    // [2][256] colsum of y
#define OFF_SPE  6308352u    // [2][16][256] colsum partials of E
#define OFF_SE   6316544u    // [2][256] colsum of E
#define OFF_BNSS 6365184u    // [512] f32 (scale[256], shift[256])
#define OFF_HG   6365696u    // uint32 [2][4096][128] bitmask (H, dense)
#define OFF_XA   7414272u    // [2][256][64][64] f32 (NCHW, post BN+SiLU)
#define OFF_W2   9511424u    // [256*9][256] f32 reordered conv weights
#define OFF_XDT  10101248u   // [2][1024][256] f32 (px-major conv output)
// end: 10625536 floats = 42.5 MB (same footprint as round 1)

// ---------- transpose x[b][c][n] -> xt[b][n][c] ----------
__global__ void k_transpose(const float* __restrict__ x, float* __restrict__ xt) {
  __shared__ float tile[32][33];
  const int b = blockIdx.z;
  const int n0 = blockIdx.x * 32, c0 = blockIdx.y * 32;
  const int tx = threadIdx.x, ty = threadIdx.y;
  const float* xb = x + (size_t)b * CH * NPIX;
  float* xtb = xt + (size_t)b * NPIX * CH;
#pragma unroll
  for (int k = 0; k < 4; ++k)
    tile[ty + k * 8][tx] = xb[(c0 + ty + k * 8) * NPIX + n0 + tx];
  __syncthreads();
#pragma unroll
  for (int k = 0; k < 4; ++k)
    xtb[(n0 + ty + k * 8) * CH + c0 + tx] = tile[tx][ty + k * 8];
}

// ---------- row squared norms ----------
__global__ void k_sq(const float* __restrict__ xt, float* __restrict__ sq) {
  const int row = blockIdx.x;  // 0..8191
  const int t = threadIdx.x;   // 64
  const float4 v = reinterpret_cast<const float4*>(xt + (size_t)row * CH)[t];
  float s = v.x * v.x + v.y * v.y + v.z * v.z + v.w * v.w;
#pragma unroll
  for (int off = 32; off; off >>= 1) s += __shfl_down(s, off);
  if (t == 0) sq[row] = s;
}

// ---------- Gram GEMM (fp32) with fused threshold -> bitmask ----------
__global__ __launch_bounds__(256) void k_gram(const float* __restrict__ xt,
                                              const float* __restrict__ sq,
                                              unsigned* __restrict__ hgbit) {
  __shared__ float As[16][128];
  __shared__ float Bs[16][128];
  __shared__ unsigned char bits[128][16];
  const int b = blockIdx.z;
  const int i0 = blockIdx.y * 128, j0 = blockIdx.x * 128;
  const int t = threadIdx.x;
  const int tx = t & 15, ty = t >> 4;
  const float* base = xt + (size_t)b * NPIX * CH;
  float acc[8][8];
#pragma unroll
  for (int r = 0; r < 8; ++r)
#pragma unroll
    for (int s = 0; s < 8; ++s) acc[r][s] = 0.f;

  for (int k0 = 0; k0 < CH; k0 += 16) {
#pragma unroll
    for (int q = 0; q < 2; ++q) {
      const int fi = t * 2 + q;
      const int r = fi >> 2, kq = fi & 3;
      float4 av = *reinterpret_cast<const float4*>(base + (size_t)(i0 + r) * CH + k0 + kq * 4);
      As[kq * 4 + 0][r] = av.x; As[kq * 4 + 1][r] = av.y;
      As[kq * 4 + 2][r] = av.z; As[kq * 4 + 3][r] = av.w;
      float4 bv = *reinterpret_cast<const float4*>(base + (size_t)(j0 + r) * CH + k0 + kq * 4);
      Bs[kq * 4 + 0][r] = bv.x; Bs[kq * 4 + 1][r] = bv.y;
      Bs[kq * 4 + 2][r] = bv.z; Bs[kq * 4 + 3][r] = bv.w;
    }
    __syncthreads();
#pragma unroll
    for (int kk = 0; kk < 16; ++kk) {
      float a[8], bb[8];
      *(float4*)&a[0]  = *(const float4*)&As[kk][ty * 8];
      *(float4*)&a[4]  = *(const float4*)&As[kk][ty * 8 + 4];
      *(float4*)&bb[0] = *(const float4*)&Bs[kk][tx * 8];
      *(float4*)&bb[4] = *(const float4*)&Bs[kk][tx * 8 + 4];
#pragma unroll
      for (int r = 0; r < 8; ++r)
#pragma unroll
        for (int s = 0; s < 8; ++s) acc[r][s] += a[r] * bb[s];
    }
    __syncthreads();
  }
  float sqi[8], sqj[8];
#pragma unroll
  for (int r = 0; r < 8; ++r) sqi[r] = sq[b * NPIX + i0 + ty * 8 + r];
#pragma unroll
  for (int s = 0; s < 8; ++s) sqj[s] = sq[b * NPIX + j0 + tx * 8 + s];
#pragma unroll
  for (int r = 0; r < 8; ++r) {
    unsigned m = 0;
#pragma unroll
    for (int s = 0; s < 8; ++s) {
      const float d2 = sqi[r] + sqj[s] - 2.f * acc[r][s];
      m |= (d2 < 100.f) ? (1u << s) : 0u;
    }
    bits[ty * 8 + r][tx] = (unsigned char)m;
  }
  __syncthreads();
#pragma unroll
  for (int q = 0; q < 2; ++q) {
    const int w = t + q * 256;              // 0..511
    const int row = w >> 2, wc = w & 3;
    const unsigned word = (unsigned)bits[row][wc * 4] |
                          ((unsigned)bits[row][wc * 4 + 1] << 8) |
                          ((unsigned)bits[row][wc * 4 + 2] << 16) |
                          ((unsigned)bits[row][wc * 4 + 3] << 24);
    hgbit[(size_t)(b * NPIX + i0 + row) * 128 + (j0 >> 5) + wc] = word;
  }
}

// ---------- generic 64x64 GEMM: C = A(MxK) * B(NxK)^T + bias ----------
__global__ __launch_bounds__(256) void k_gemm_nt64(const float* __restrict__ A,
                                                   const float* __restrict__ B,
                                                   float* __restrict__ C,
                                                   const float* __restrict__ bias,
                                                   int M, int N, int K, int biasRow,
                                                   int aStride, int bStride, int cStride) {
  A += (size_t)blockIdx.z * aStride;
  B += (size_t)blockIdx.z * bStride;
  C += (size_t)blockIdx.z * cStride;
  __shared__ float As[16][64];
  __shared__ float Bs[16][64];
  const int m0 = blockIdx.y * 64, n0 = blockIdx.x * 64;
  const int t = threadIdx.x, tx = t & 15, ty = t >> 4;
  float acc[4][4];
#pragma unroll
  for (int r = 0; r < 4; ++r)
#pragma unroll
    for (int s = 0; s < 4; ++s) acc[r][s] = 0.f;

  for (int k0 = 0; k0 < K; k0 += 16) {
    const int r = t >> 2, kq = t & 3;
    float4 av = *reinterpret_cast<const float4*>(A + (size_t)(m0 + r) * K + k0 + kq * 4);
    As[kq * 4 + 0][r] = av.x; As[kq * 4 + 1][r] = av.y;
    As[kq * 4 + 2][r] = av.z; As[kq * 4 + 3][r] = av.w;
    float4 bv = *reinterpret_cast<const float4*>(B + (size_t)(n0 + r) * K + k0 + kq * 4);
    Bs[kq * 4 + 0][r] = bv.x; Bs[kq * 4 + 1][r] = bv.y;
    Bs[kq * 4 + 2][r] = bv.z; Bs[kq * 4 + 3][r] = bv.w;
    __syncthreads();
#pragma unroll
    for (int kk = 0; kk < 16; ++kk) {
      float4 a4 = *(const float4*)&As[kk][ty * 4];
      float4 b4 = *(const float4*)&Bs[kk][tx * 4];
      const float a[4] = {a4.x, a4.y, a4.z, a4.w};
      const float bb[4] = {b4.x, b4.y, b4.z, b4.w};
#pragma unroll
      for (int r = 0; r < 4; ++r)
#pragma unroll
        for (int s = 0; s < 4; ++s) acc[r][s] += a[r] * bb[s];
    }
    __syncthreads();
  }
#pragma unroll
  for (int r = 0; r < 4; ++r) {
    float4 v;
    const int row = m0 + ty * 4 + r;
    float* cp = C + (size_t)row * N + n0 + tx * 4;
    if (biasRow) {
      const float bv = bias[row];
      v.x = acc[r][0] + bv; v.y = acc[r][1] + bv; v.z = acc[r][2] + bv; v.w = acc[r][3] + bv;
    } else {
      v.x = acc[r][0] + bias[n0 + tx * 4 + 0];
      v.y = acc[r][1] + bias[n0 + tx * 4 + 1];
      v.z = acc[r][2] + bias[n0 + tx * 4 + 2];
      v.w = acc[r][3] + bias[n0 + tx * 4 + 3];
    }
    *(float4*)cp = v;
  }
}

// ---------- column-sum partials: Sp[b][chunk][c] = sum over 256 rows ----------
__global__ void k_colsum(const float* __restrict__ src, float* __restrict__ Sp) {
  const int b = blockIdx.y, chunk = blockIdx.x, t = threadIdx.x;  // 16x2 blocks, 256 thr
  const float* p = src + ((size_t)b * NPIX + chunk * 256) * CH;
  float s = 0.f;
  for (int r = 0; r < 256; ++r) s += p[r * CH + t];
  Sp[((size_t)b * 16 + chunk) * CH + t] = s;
}

__global__ void k_colfin(const float* __restrict__ Sp, float* __restrict__ S) {
  const int b = blockIdx.x, t = threadIdx.x;  // 2 blocks, 256 thr
  float s = 0.f;
#pragma unroll
  for (int i = 0; i < 16; ++i) s += Sp[((size_t)b * 16 + i) * CH + t];
  S[b * CH + t] = s;
}

// ---------- complement mean-aggregation: (S - sum_{j in ~H_i} src_j)/|H_i| ----------
__global__ void k_aggc(const unsigned* __restrict__ hgbit, const float* __restrict__ src,
                       const float* __restrict__ S, const float* __restrict__ resid,
                       float* __restrict__ dst) {
  const int row = blockIdx.x;  // b*4096 + i
  const int b = row >> 12;
  const int t = threadIdx.x;   // 256
  __shared__ unsigned wrd[128];
  if (t < 128) wrd[t] = ~hgbit[(size_t)row * 128 + t];
  __syncthreads();
  float acc = 0.f;
  int nd = 0;                  // complement degree
  const float* sb = src + (size_t)b * NPIX * CH;
  for (int w = 0; w < 128; ++w) {
    unsigned u = wrd[w];
    nd += __popc(u);
    while (u) {
      const int j = (w << 5) + __ffs(u) - 1;
      u &= u - 1;
      acc += sb[(size_t)j * CH + t];
    }
  }
  float r = (S[b * CH + t] - acc) / (float)(NPIX - nd);
  if (resid) r += resid[(size_t)row * CH + t];
  dst[(size_t)row * CH + t] = r;
}

// ---------- BN statistics: per-block partial sums ----------
__global__ void k_bnstat(const float* __restrict__ xn, float* __restrict__ part) {
  const int t = threadIdx.x, blk = blockIdx.x;  // 128 blocks x 64 rows
  float s = 0.f, ss = 0.f;
  const float* p = xn + (size_t)blk * 64 * CH;
  for (int r = 0; r < 64; ++r) {
    const float v = p[r * CH + t];
    s += v; ss += v * v;
  }
  part[blk * 512 + t] = s;
  part[blk * 512 + 256 + t] = ss;
}

__global__ void k_bnfin(const float* __restrict__ part, const float* __restrict__ gamma,
                        const float* __restrict__ beta, float* __restrict__ bnss) {
  const int t = threadIdx.x;  // 256
  float s = 0.f, ss = 0.f;
  for (int i = 0; i < 128; ++i) { s += part[i * 512 + t]; ss += part[i * 512 + 256 + t]; }
  const float mean = s * (1.f / 8192.f);
  const float var = ss * (1.f / 8192.f) - mean * mean;
  const float inv = rsqrtf(var + 1e-5f);
  const float sc = gamma[t] * inv;
  bnss[t] = sc;
  bnss[256 + t] = beta[t] - mean * sc;
}

// ---------- BN apply + SiLU + transpose [b][n][c] -> [b][c][n] ----------
__global__ void k_bnapply(const float* __restrict__ xn, const float* __restrict__ bnss,
                          float* __restrict__ xa) {
  __shared__ float tile[32][33];
  const int b = blockIdx.z;
  const int n0 = blockIdx.x * 32, c0 = blockIdx.y * 32;
  const int tx = threadIdx.x, ty = threadIdx.y;
  const float* xb = xn + (size_t)b * NPIX * CH;
  float* ob = xa + (size_t)b * CH * NPIX;
#pragma unroll
  for (int k = 0; k < 4; ++k)
    tile[ty + k * 8][tx] = xb[(n0 + ty + k * 8) * CH + c0 + tx];
  __syncthreads();
#pragma unroll
  for (int k = 0; k < 4; ++k) {
    const int c = c0 + ty + k * 8;
    const float u = tile[tx][ty + k * 8] * bnss[c] + bnss[256 + c];
    const float sil = u / (1.f + expf(-u));
    ob[(size_t)c * NPIX + n0 + tx] = sil;
  }
}

// ---------- reorder conv weights [oc][c][kh][kw] -> [c*9][oc] ----------
__global__ void k_w2(const float* __restrict__ w, float* __restrict__ w2) {
  const int i = blockIdx.x * 256 + threadIdx.x;  // 589824
  const int oc = i / (CH * 9);
  const int rem = i % (CH * 9);  // c*9 + kh*3 + kw
  w2[(size_t)rem * 256 + oc] = w[i];
}

// ---------- 3x3 stride-2 conv, channel-split 2-way -> partials [half][b][px][oc] ----------
__global__ __launch_bounds__(256) void k_conv2(const float* __restrict__ xa,
                                               const float* __restrict__ w2,
                                               float* __restrict__ xpart) {
  __shared__ float p_s[4 * 17 * 19];  // [c][17][19] padded rows
  const int bz = blockIdx.z;           // 0..3: b*2 + half
  const int b = bz >> 1, half = bz & 1;
  const int ocg = blockIdx.y;          // 8 -> 32 oc each
  const int sp = blockIdx.x;           // 16 -> 8x8 px tiles
  const int oh0 = (sp >> 2) * 8, ow0 = (sp & 3) * 8;
  const int t = threadIdx.x;
  const int w = t >> 6, lane = t & 63;
  const int ph = lane >> 3, pw = lane & 7;
  const int ocb = __builtin_amdgcn_readfirstlane(ocg * 32 + w * 8);
  float acc[8];
#pragma unroll
  for (int o = 0; o < 8; ++o) acc[o] = 0.f;
  const float* xb = xa + (size_t)b * CH * NPIX;

  for (int cc = 0; cc < 32; ++cc) {
    const int c4 = half * 32 + cc;
    __syncthreads();
    for (int e = t; e < 4 * 289; e += 256) {
      const int c = e / 289, rem = e % 289, r = rem / 17, col = rem % 17;
      const int ih = oh0 * 2 + r, iw = ow0 * 2 + col;
      const float v = (ih < 64 && iw < 64) ? xb[((c4 * 4 + c) * 64 + ih) * 64 + iw] : 0.f;
      p_s[c * 323 + r * 19 + col] = v;
    }
    __syncthreads();
#pragma unroll
    for (int cl = 0; cl < 4; ++cl) {
      const int cg = c4 * 4 + cl;
#pragma unroll
      for (int kh = 0; kh < 3; ++kh) {
#pragma unroll
        for (int kw = 0; kw < 3; ++kw) {
          const float in = p_s[cl * 323 + (2 * ph + kh) * 19 + 2 * pw + kw];
          const float* wv = w2 + (size_t)(cg * 9 + kh * 3 + kw) * 256 + ocb;
#pragma unroll
          for (int o = 0; o < 8; ++o) acc[o] += in * wv[o];
        }
      }
    }
  }
  const int px = (oh0 + ph) * 32 + (ow0 + pw);
  float* out = xpart + (((size_t)(half * 2 + b)) * 1024 + px) * 256 + ocb;
  float4 v0, v1;
  v0.x = acc[0]; v0.y = acc[1]; v0.z = acc[2]; v0.w = acc[3];
  v1.x = acc[4]; v1.y = acc[5]; v1.z = acc[6]; v1.w = acc[7];
  *(float4*)out = v0;
  *(float4*)(out + 4) = v1;
}

// ---------- merge conv partials + bias -> xdT[b][px][oc] ----------
__global__ void k_convmerge(const float* __restrict__ xpart, const float* __restrict__ bias,
                            float* __restrict__ xdT) {
  const int i = blockIdx.x * 256 + threadIdx.x;  // 524288
  xdT[i] = xpart[i] + xpart[i + 524288] + bias[i & 255];
}

extern "C" void kernel_launch(void* const* d_in, const int* in_sizes, int n_in,
                              void* d_out, int out_size, void* d_ws, size_t ws_size,
                              hipStream_t stream) {
  const float* x     = (const float*)d_in[0];
  const float* fc_w  = (const float*)d_in[1];
  const float* fc_b  = (const float*)d_in[2];
  const float* gamma = (const float*)d_in[3];
  const float* beta  = (const float*)d_in[4];
  const float* dw    = (const float*)d_in[5];
  const float* db    = (const float*)d_in[6];
  const float* ow    = (const float*)d_in[7];
  const float* ob    = (const float*)d_in[8];

  float* ws   = (float*)d_ws;
  float* xt   = ws + OFF_XT;
  float* y    = ws + OFF_Y;     // later reused as xnew
  float* E    = ws + OFF_E;     // later reused as conv partials
  float* sqv  = ws + OFF_SQ;
  float* part = ws + OFF_PART;
  float* Spy  = ws + OFF_SPY;
  float* Sy   = ws + OFF_SY;
  float* Spe  = ws + OFF_SPE;
  float* Se   = ws + OFF_SE;
  float* bnss = ws + OFF_BNSS;
  unsigned* hg = (unsigned*)(ws + OFF_HG);
  float* xa   = ws + OFF_XA;
  float* w2   = ws + OFF_W2;
  float* xdT  = ws + OFF_XDT;
  float* out  = (float*)d_out;

  k_transpose<<<dim3(128, 8, 2), dim3(32, 8), 0, stream>>>(x, xt);
  k_sq<<<8192, 64, 0, stream>>>(xt, sqv);
  k_w2<<<2304, 256, 0, stream>>>(dw, w2);
  k_gram<<<dim3(32, 32, 2), 256, 0, stream>>>(xt, sqv, hg);
  // y = xf @ fc_w^T + fc_b : M=8192 N=256 K=256
  k_gemm_nt64<<<dim3(4, 128, 1), 256, 0, stream>>>(xt, fc_w, y, fc_b,
                                                   8192, 256, 256, 0, 0, 0, 0);
  // vertex -> edge (complement trick)
  k_colsum<<<dim3(16, 2), 256, 0, stream>>>(y, Spy);
  k_colfin<<<2, 256, 0, stream>>>(Spy, Sy);
  k_aggc<<<8192, 256, 0, stream>>>(hg, y, Sy, nullptr, E);
  // edge -> vertex + residual
  k_colsum<<<dim3(16, 2), 256, 0, stream>>>(E, Spe);
  k_colfin<<<2, 256, 0, stream>>>(Spe, Se);
  k_aggc<<<8192, 256, 0, stream>>>(hg, E, Se, xt, y);
  k_bnstat<<<128, 256, 0, stream>>>(y, part);
  k_bnfin<<<1, 256, 0, stream>>>(part, gamma, beta, bnss);
  k_bnapply<<<dim3(128, 8, 2), dim3(32, 8), 0, stream>>>(y, bnss, xa);
  k_conv2<<<dim3(16, 8, 4), 256, 0, stream>>>(xa, w2, E);
  k_convmerge<<<2048, 256, 0, stream>>>(E, db, xdT);
  // out = out_w @ xdT^T + out_b : per batch M=512 N=1024 K=256 (row bias)
  k_gemm_nt64<<<dim3(16, 8, 2), 256, 0, stream>>>(ow, xdT, out, ob,
                                                  512, 1024, 256, 1,
                                                  0, 1024 * 256, 512 * 1024);
}

// Round 3
// 550.710 us; speedup vs baseline: 13.7280x; 1.7465x over previous
//
#include <hip/hip_runtime.h>
#include <hip/hip_bf16.h>
#include <math.h>

#define NPIX 4096
#define CH   256

// ---- ws float offsets ----
#define OFF_XT   0u          // [2][4096][256] f32
#define OFF_Y    2097152u    // [2][4096][256] f32 (reused as xnew after v-agg)
#define OFF_E    4194304u    // [2][4096][256] f32 (reused as conv partials)
#define OFF_SQ   6291456u    // [2][4096] f32
#define OFF_PART 6299648u    // [128][512] f32 BN partials
#define OFF_BNSS 6365184u    // [512] f32
#define OFF_HG   6365696u    // uint32 [2][4096][128] bitmask (H, dense)
#define OFF_XA   7414272u    // [2][256][64][64] f32 — ALSO aliases xbh (bf16, phase 1) and CSR idx pool (phase 2)
#define OFF_W2   9511424u    // [256*9][256] f32 reordered conv weights
#define OFF_XDT  10101248u   // [2][1024][256] f32
#define OFF_SPY  10625536u   // [2][64][256] colsum partials (y)
#define OFF_SY   10658304u   // [2][256]
#define OFF_SPE  10658816u   // [2][64][256] colsum partials (E)
#define OFF_SE   10691584u   // [2][256]
#define OFF_DEGC 10692096u   // [8192] int complement degree
#define OFF_CSRO 10700288u   // [8193] int csr offsets
// end: 10708488 floats = 42.8 MB

typedef __attribute__((ext_vector_type(8))) short bf16x8;
typedef __attribute__((ext_vector_type(16))) float f32x16;

// ---------- transpose x[b][c][n] -> xt[b][n][c] (f32) + xbh (bf16) ----------
__global__ void k_transpose(const float* __restrict__ x, float* __restrict__ xt,
                            __hip_bfloat16* __restrict__ xbh) {
  __shared__ float tile[32][33];
  const int b = blockIdx.z;
  const int n0 = blockIdx.x * 32, c0 = blockIdx.y * 32;
  const int tx = threadIdx.x, ty = threadIdx.y;
  const float* xb = x + (size_t)b * CH * NPIX;
  float* xtb = xt + (size_t)b * NPIX * CH;
  __hip_bfloat16* xhb = xbh + (size_t)b * NPIX * CH;
#pragma unroll
  for (int k = 0; k < 4; ++k)
    tile[ty + k * 8][tx] = xb[(c0 + ty + k * 8) * NPIX + n0 + tx];
  __syncthreads();
#pragma unroll
  for (int k = 0; k < 4; ++k) {
    const float v = tile[tx][ty + k * 8];
    const size_t o = (size_t)(n0 + ty + k * 8) * CH + c0 + tx;
    xtb[o] = v;
    xhb[o] = __float2bfloat16(v);
  }
}

// ---------- row squared norms (f32) ----------
__global__ void k_sq(const float* __restrict__ xt, float* __restrict__ sq) {
  const int row = blockIdx.x;  // 0..8191
  const int t = threadIdx.x;   // 64
  const float4 v = reinterpret_cast<const float4*>(xt + (size_t)row * CH)[t];
  float s = v.x * v.x + v.y * v.y + v.z * v.z + v.w * v.w;
#pragma unroll
  for (int off = 32; off; off >>= 1) s += __shfl_down(s, off);
  if (t == 0) sq[row] = s;
}

// ---------- Gram via bf16 MFMA, fused threshold -> incidence bitmask ----------
__global__ __launch_bounds__(256) void k_gram_mfma(const __hip_bfloat16* __restrict__ xbh,
                                                   const float* __restrict__ sq,
                                                   unsigned* __restrict__ hgbit) {
  const int b = blockIdx.z;
  const int i0 = blockIdx.y * 128, j0 = blockIdx.x * 128;
  const int t = threadIdx.x;
  const int lane = t & 63, wid = t >> 6;
  const int wm = wid >> 1, wn = wid & 1;
  const int c = lane & 31, h = lane >> 5;
  const short* base = (const short*)xbh + (size_t)b * NPIX * CH;
  const int ibase = i0 + wm * 64;
  const int jbase = j0 + wn * 64;

  f32x16 acc[2][2];
#pragma unroll
  for (int m = 0; m < 2; ++m)
#pragma unroll
    for (int n = 0; n < 2; ++n)
#pragma unroll
      for (int r = 0; r < 16; ++r) acc[m][n][r] = 0.f;

  const short* pa0 = base + (size_t)(ibase + c) * CH + h * 8;
  const short* pa1 = pa0 + 32 * CH;
  const short* pb0 = base + (size_t)(jbase + c) * CH + h * 8;
  const short* pb1 = pb0 + 32 * CH;

  for (int k0 = 0; k0 < CH; k0 += 16) {
    const bf16x8 a0 = *(const bf16x8*)(pa0 + k0);
    const bf16x8 a1 = *(const bf16x8*)(pa1 + k0);
    const bf16x8 b0 = *(const bf16x8*)(pb0 + k0);
    const bf16x8 b1 = *(const bf16x8*)(pb1 + k0);
    acc[0][0] = __builtin_amdgcn_mfma_f32_32x32x16_bf16(a0, b0, acc[0][0], 0, 0, 0);
    acc[0][1] = __builtin_amdgcn_mfma_f32_32x32x16_bf16(a0, b1, acc[0][1], 0, 0, 0);
    acc[1][0] = __builtin_amdgcn_mfma_f32_32x32x16_bf16(a1, b0, acc[1][0], 0, 0, 0);
    acc[1][1] = __builtin_amdgcn_mfma_f32_32x32x16_bf16(a1, b1, acc[1][1], 0, 0, 0);
  }

  const int sqb = b * NPIX;
#pragma unroll
  for (int m = 0; m < 2; ++m) {
    // rows this lane owns: m*32 + (reg&3) + 8*(reg>>2) + 4*h
    float4 sqa[4];
#pragma unroll
    for (int q = 0; q < 4; ++q)
      sqa[q] = *(const float4*)(sq + sqb + ibase + m * 32 + q * 8 + 4 * h);
#pragma unroll
    for (int n = 0; n < 2; ++n) {
      const float sj = sq[sqb + jbase + n * 32 + c];
      const int wj = (jbase + n * 32) >> 5;
#pragma unroll
      for (int q = 0; q < 4; ++q) {
        const float sqq[4] = {sqa[q].x, sqa[q].y, sqa[q].z, sqa[q].w};
#pragma unroll
        for (int rr = 0; rr < 4; ++rr) {
          const int reg = q * 4 + rr;
          const float d2 = sqq[rr] + sj - 2.f * acc[m][n][reg];
          const unsigned long long bal = __ballot(d2 < 100.f);
          // low 32 bits: rows with h=0 (lanes 0-31, bit=col); high: h=1
          if ((lane & 31) == reg) {
            const int row = ibase + m * 32 + rr + 8 * q + 4 * h;
            const unsigned wd = h ? (unsigned)(bal >> 32) : (unsigned)bal;
            hgbit[(size_t)(sqb + row) * 128 + wj] = wd;
          }
        }
      }
    }
  }
}

// ---------- complement degree per row ----------
__global__ void k_deg(const unsigned* __restrict__ hg, int* __restrict__ degc) {
  const int row = blockIdx.x, l = threadIdx.x;  // 64 thr
  const unsigned w0 = hg[(size_t)row * 128 + l * 2];
  const unsigned w1 = hg[(size_t)row * 128 + l * 2 + 1];
  int n = __popc(~w0) + __popc(~w1);
#pragma unroll
  for (int off = 32; off; off >>= 1) n += __shfl_down(n, off);
  if (l == 0) degc[row] = n;
}

// ---------- exclusive prefix sum of 8192 degrees (1 block) ----------
__global__ void k_scan(const int* __restrict__ degc, int* __restrict__ csroff) {
  __shared__ int ps[256];
  const int t = threadIdx.x;
  const int base = t * 32;
  int s = 0;
  for (int i = 0; i < 32; ++i) s += degc[base + i];
  ps[t] = s;
  __syncthreads();
  for (int d = 1; d < 256; d <<= 1) {
    const int v = (t >= d) ? ps[t - d] : 0;
    __syncthreads();
    ps[t] += v;
    __syncthreads();
  }
  int run = (t == 0) ? 0 : ps[t - 1];
  for (int i = 0; i < 32; ++i) { csroff[base + i] = run; run += degc[base + i]; }
  if (t == 255) csroff[8192] = run;
}

// ---------- fill CSR column indices (complement edges) ----------
__global__ void k_fill(const unsigned* __restrict__ hg, const int* __restrict__ csroff,
                       unsigned short* __restrict__ idx) {
  const int row = blockIdx.x, l = threadIdx.x;  // 64 thr
  unsigned w0 = ~hg[(size_t)row * 128 + l * 2];
  unsigned w1 = ~hg[(size_t)row * 128 + l * 2 + 1];
  const int n = __popc(w0) + __popc(w1);
  int p = n;
#pragma unroll
  for (int d = 1; d < 64; d <<= 1) {
    const int v = __shfl_up(p, d);
    if (l >= d) p += v;
  }
  p -= n;  // exclusive prefix within wave
  int wpos = csroff[row] + p;
  int c0 = l * 64;
  while (w0) { const int bb = __ffs(w0) - 1; w0 &= w0 - 1; idx[wpos++] = (unsigned short)(c0 + bb); }
  c0 += 32;
  while (w1) { const int bb = __ffs(w1) - 1; w1 &= w1 - 1; idx[wpos++] = (unsigned short)(c0 + bb); }
}

// ---------- generic 64x64 GEMM: C = A(MxK) * B(NxK)^T + bias ----------
__global__ __launch_bounds__(256) void k_gemm_nt64(const float* __restrict__ A,
                                                   const float* __restrict__ B,
                                                   float* __restrict__ C,
                                                   const float* __restrict__ bias,
                                                   int M, int N, int K, int biasRow,
                                                   int aStride, int bStride, int cStride) {
  A += (size_t)blockIdx.z * aStride;
  B += (size_t)blockIdx.z * bStride;
  C += (size_t)blockIdx.z * cStride;
  __shared__ float As[16][64];
  __shared__ float Bs[16][64];
  const int m0 = blockIdx.y * 64, n0 = blockIdx.x * 64;
  const int t = threadIdx.x, tx = t & 15, ty = t >> 4;
  float acc[4][4];
#pragma unroll
  for (int r = 0; r < 4; ++r)
#pragma unroll
    for (int s = 0; s < 4; ++s) acc[r][s] = 0.f;

  for (int k0 = 0; k0 < K; k0 += 16) {
    const int r = t >> 2, kq = t & 3;
    float4 av = *reinterpret_cast<const float4*>(A + (size_t)(m0 + r) * K + k0 + kq * 4);
    As[kq * 4 + 0][r] = av.x; As[kq * 4 + 1][r] = av.y;
    As[kq * 4 + 2][r] = av.z; As[kq * 4 + 3][r] = av.w;
    float4 bv = *reinterpret_cast<const float4*>(B + (size_t)(n0 + r) * K + k0 + kq * 4);
    Bs[kq * 4 + 0][r] = bv.x; Bs[kq * 4 + 1][r] = bv.y;
    Bs[kq * 4 + 2][r] = bv.z; Bs[kq * 4 + 3][r] = bv.w;
    __syncthreads();
#pragma unroll
    for (int kk = 0; kk < 16; ++kk) {
      float4 a4 = *(const float4*)&As[kk][ty * 4];
      float4 b4 = *(const float4*)&Bs[kk][tx * 4];
      const float a[4] = {a4.x, a4.y, a4.z, a4.w};
      const float bb[4] = {b4.x, b4.y, b4.z, b4.w};
#pragma unroll
      for (int r = 0; r < 4; ++r)
#pragma unroll
        for (int s = 0; s < 4; ++s) acc[r][s] += a[r] * bb[s];
    }
    __syncthreads();
  }
#pragma unroll
  for (int r = 0; r < 4; ++r) {
    float4 v;
    const int row = m0 + ty * 4 + r;
    float* cp = C + (size_t)row * N + n0 + tx * 4;
    if (biasRow) {
      const float bv = bias[row];
      v.x = acc[r][0] + bv; v.y = acc[r][1] + bv; v.z = acc[r][2] + bv; v.w = acc[r][3] + bv;
    } else {
      v.x = acc[r][0] + bias[n0 + tx * 4 + 0];
      v.y = acc[r][1] + bias[n0 + tx * 4 + 1];
      v.z = acc[r][2] + bias[n0 + tx * 4 + 2];
      v.w = acc[r][3] + bias[n0 + tx * 4 + 3];
    }
    *(float4*)cp = v;
  }
}

// ---------- column-sum partials: Sp[b][chunk][c] = sum over 64 rows ----------
__global__ void k_colsum(const float* __restrict__ src, float* __restrict__ Sp) {
  const int b = blockIdx.y, chunk = blockIdx.x, t = threadIdx.x;  // 64x2 blocks
  const float* p = src + ((size_t)b * NPIX + chunk * 64) * CH;
  float s = 0.f;
  for (int r = 0; r < 64; ++r) s += p[r * CH + t];
  Sp[((size_t)b * 64 + chunk) * CH + t] = s;
}

__global__ void k_colfin(const float* __restrict__ Sp, float* __restrict__ S) {
  const int b = blockIdx.x, t = threadIdx.x;
  float s = 0.f;
#pragma unroll
  for (int i = 0; i < 64; ++i) s += Sp[((size_t)b * 64 + i) * CH + t];
  S[b * CH + t] = s;
}

// ---------- complement mean-aggregation via CSR ----------
__global__ void k_aggc2(const int* __restrict__ csroff, const unsigned short* __restrict__ idx,
                        const float* __restrict__ src, const float* __restrict__ S,
                        const float* __restrict__ resid, float* __restrict__ dst) {
  const int row = blockIdx.x;  // b*4096 + i
  const int b = row >> 12;
  const int t = threadIdx.x;   // 256
  const int o0 = csroff[row], o1 = csroff[row + 1];
  const float* sb = src + (size_t)b * NPIX * CH;
  float a0 = 0.f, a1 = 0.f, a2 = 0.f, a3 = 0.f;
  int e = o0;
  for (; e + 4 <= o1; e += 4) {
    const int j0 = idx[e], j1 = idx[e + 1], j2 = idx[e + 2], j3 = idx[e + 3];
    a0 += sb[j0 * CH + t];
    a1 += sb[j1 * CH + t];
    a2 += sb[j2 * CH + t];
    a3 += sb[j3 * CH + t];
  }
  for (; e < o1; ++e) a0 += sb[(int)idx[e] * CH + t];
  const int nd = o1 - o0;
  float r = (nd >= NPIX) ? 0.f
          : (S[b * CH + t] - (a0 + a1 + a2 + a3)) / (float)(NPIX - nd);
  if (resid) r += resid[(size_t)row * CH + t];
  dst[(size_t)row * CH + t] = r;
}

// ---------- BN statistics ----------
__global__ void k_bnstat(const float* __restrict__ xn, float* __restrict__ part) {
  const int t = threadIdx.x, blk = blockIdx.x;  // 128 blocks x 64 rows
  float s = 0.f, ss = 0.f;
  const float* p = xn + (size_t)blk * 64 * CH;
  for (int r = 0; r < 64; ++r) {
    const float v = p[r * CH + t];
    s += v; ss += v * v;
  }
  part[blk * 512 + t] = s;
  part[blk * 512 + 256 + t] = ss;
}

__global__ void k_bnfin(const float* __restrict__ part, const float* __restrict__ gamma,
                        const float* __restrict__ beta, float* __restrict__ bnss) {
  const int t = threadIdx.x;  // 256
  float s = 0.f, ss = 0.f;
  for (int i = 0; i < 128; ++i) { s += part[i * 512 + t]; ss += part[i * 512 + 256 + t]; }
  const float mean = s * (1.f / 8192.f);
  const float var = ss * (1.f / 8192.f) - mean * mean;
  const float inv = rsqrtf(var + 1e-5f);
  const float sc = gamma[t] * inv;
  bnss[t] = sc;
  bnss[256 + t] = beta[t] - mean * sc;
}

// ---------- BN apply + SiLU + transpose [b][n][c] -> [b][c][n] ----------
__global__ void k_bnapply(const float* __restrict__ xn, const float* __restrict__ bnss,
                          float* __restrict__ xa) {
  __shared__ float tile[32][33];
  const int b = blockIdx.z;
  const int n0 = blockIdx.x * 32, c0 = blockIdx.y * 32;
  const int tx = threadIdx.x, ty = threadIdx.y;
  const float* xb = xn + (size_t)b * NPIX * CH;
  float* ob = xa + (size_t)b * CH * NPIX;
#pragma unroll
  for (int k = 0; k < 4; ++k)
    tile[ty + k * 8][tx] = xb[(n0 + ty + k * 8) * CH + c0 + tx];
  __syncthreads();
#pragma unroll
  for (int k = 0; k < 4; ++k) {
    const int c = c0 + ty + k * 8;
    const float u = tile[tx][ty + k * 8] * bnss[c] + bnss[256 + c];
    const float sil = u / (1.f + expf(-u));
    ob[(size_t)c * NPIX + n0 + tx] = sil;
  }
}

// ---------- reorder conv weights [oc][c][kh][kw] -> [c*9][oc] ----------
__global__ void k_w2(const float* __restrict__ w, float* __restrict__ w2) {
  const int i = blockIdx.x * 256 + threadIdx.x;  // 589824
  const int oc = i / (CH * 9);
  const int rem = i % (CH * 9);
  w2[(size_t)rem * 256 + oc] = w[i];
}

// ---------- 3x3 stride-2 conv, channel-split 2-way -> partials ----------
__global__ __launch_bounds__(256) void k_conv2(const float* __restrict__ xa,
                                               const float* __restrict__ w2,
                                               float* __restrict__ xpart) {
  __shared__ float p_s[4 * 17 * 19];
  const int bz = blockIdx.z;
  const int b = bz >> 1, half = bz & 1;
  const int ocg = blockIdx.y;
  const int sp = blockIdx.x;
  const int oh0 = (sp >> 2) * 8, ow0 = (sp & 3) * 8;
  const int t = threadIdx.x;
  const int w = t >> 6, lane = t & 63;
  const int ph = lane >> 3, pw = lane & 7;
  const int ocb = __builtin_amdgcn_readfirstlane(ocg * 32 + w * 8);
  float acc[8];
#pragma unroll
  for (int o = 0; o < 8; ++o) acc[o] = 0.f;
  const float* xb = xa + (size_t)b * CH * NPIX;

  for (int cc = 0; cc < 32; ++cc) {
    const int c4 = half * 32 + cc;
    __syncthreads();
    for (int e = t; e < 4 * 289; e += 256) {
      const int c = e / 289, rem = e % 289, r = rem / 17, col = rem % 17;
      const int ih = oh0 * 2 + r, iw = ow0 * 2 + col;
      const float v = (ih < 64 && iw < 64) ? xb[((c4 * 4 + c) * 64 + ih) * 64 + iw] : 0.f;
      p_s[c * 323 + r * 19 + col] = v;
    }
    __syncthreads();
#pragma unroll
    for (int cl = 0; cl < 4; ++cl) {
      const int cg = c4 * 4 + cl;
#pragma unroll
      for (int kh = 0; kh < 3; ++kh) {
#pragma unroll
        for (int kw = 0; kw < 3; ++kw) {
          const float in = p_s[cl * 323 + (2 * ph + kh) * 19 + 2 * pw + kw];
          const float* wv = w2 + (size_t)(cg * 9 + kh * 3 + kw) * 256 + ocb;
#pragma unroll
          for (int o = 0; o < 8; ++o) acc[o] += in * wv[o];
        }
      }
    }
  }
  const int px = (oh0 + ph) * 32 + (ow0 + pw);
  float* out = xpart + (((size_t)(half * 2 + b)) * 1024 + px) * 256 + ocb;
  float4 v0, v1;
  v0.x = acc[0]; v0.y = acc[1]; v0.z = acc[2]; v0.w = acc[3];
  v1.x = acc[4]; v1.y = acc[5]; v1.z = acc[6]; v1.w = acc[7];
  *(float4*)out = v0;
  *(float4*)(out + 4) = v1;
}

__global__ void k_convmerge(const float* __restrict__ xpart, const float* __restrict__ bias,
                            float* __restrict__ xdT) {
  const int i = blockIdx.x * 256 + threadIdx.x;  // 524288
  xdT[i] = xpart[i] + xpart[i + 524288] + bias[i & 255];
}

extern "C" void kernel_launch(void* const* d_in, const int* in_sizes, int n_in,
                              void* d_out, int out_size, void* d_ws, size_t ws_size,
                              hipStream_t stream) {
  const float* x     = (const float*)d_in[0];
  const float* fc_w  = (const float*)d_in[1];
  const float* fc_b  = (const float*)d_in[2];
  const float* gamma = (const float*)d_in[3];
  const float* beta  = (const float*)d_in[4];
  const float* dw    = (const float*)d_in[5];
  const float* db    = (const float*)d_in[6];
  const float* ow    = (const float*)d_in[7];
  const float* ob    = (const float*)d_in[8];

  float* ws   = (float*)d_ws;
  float* xt   = ws + OFF_XT;
  float* y    = ws + OFF_Y;
  float* E    = ws + OFF_E;
  float* sqv  = ws + OFF_SQ;
  float* part = ws + OFF_PART;
  float* bnss = ws + OFF_BNSS;
  unsigned* hg = (unsigned*)(ws + OFF_HG);
  float* xa   = ws + OFF_XA;
  __hip_bfloat16* xbh = (__hip_bfloat16*)(ws + OFF_XA);   // phase 1 alias
  unsigned short* csri = (unsigned short*)(ws + OFF_XA);  // phase 2 alias (cap 4M entries)
  float* w2   = ws + OFF_W2;
  float* xdT  = ws + OFF_XDT;
  float* Spy  = ws + OFF_SPY;
  float* Sy   = ws + OFF_SY;
  float* Spe  = ws + OFF_SPE;
  float* Se   = ws + OFF_SE;
  int*   degc = (int*)(ws + OFF_DEGC);
  int*   csro = (int*)(ws + OFF_CSRO);
  float* out  = (float*)d_out;

  k_transpose<<<dim3(128, 8, 2), dim3(32, 8), 0, stream>>>(x, xt, xbh);
  k_sq<<<8192, 64, 0, stream>>>(xt, sqv);
  k_gram_mfma<<<dim3(32, 32, 2), 256, 0, stream>>>(xbh, sqv, hg);
  // build complement CSR (overwrites xbh region — dead after gram)
  k_deg<<<8192, 64, 0, stream>>>(hg, degc);
  k_scan<<<1, 256, 0, stream>>>(degc, csro);
  k_fill<<<8192, 64, 0, stream>>>(hg, csro, csri);
  // y = xf @ fc_w^T + fc_b
  k_gemm_nt64<<<dim3(4, 128, 1), 256, 0, stream>>>(xt, fc_w, y, fc_b,
                                                   8192, 256, 256, 0, 0, 0, 0);
  // vertex -> edge (complement trick)
  k_colsum<<<dim3(64, 2), 256, 0, stream>>>(y, Spy);
  k_colfin<<<2, 256, 0, stream>>>(Spy, Sy);
  k_aggc2<<<8192, 256, 0, stream>>>(csro, csri, y, Sy, nullptr, E);
  // edge -> vertex + residual
  k_colsum<<<dim3(64, 2), 256, 0, stream>>>(E, Spe);
  k_colfin<<<2, 256, 0, stream>>>(Spe, Se);
  k_aggc2<<<8192, 256, 0, stream>>>(csro, csri, E, Se, xt, y);
  // BN + SiLU
  k_bnstat<<<128, 256, 0, stream>>>(y, part);
  k_bnfin<<<1, 256, 0, stream>>>(part, gamma, beta, bnss);
  k_bnapply<<<dim3(128, 8, 2), dim3(32, 8), 0, stream>>>(y, bnss, xa);
  // convs
  k_w2<<<2304, 256, 0, stream>>>(dw, w2);
  k_conv2<<<dim3(16, 8, 4), 256, 0, stream>>>(xa, w2, E);
  k_convmerge<<<2048, 256, 0, stream>>>(E, db, xdT);
  k_gemm_nt64<<<dim3(16, 8, 2), 256, 0, stream>>>(ow, xdT, out, ob,
                                                  512, 1024, 256, 1,
                                                  0, 1024 * 256, 512 * 1024);
}

// Round 4
// 404.227 us; speedup vs baseline: 18.7027x; 1.3624x over previous
//
#include <hip/hip_runtime.h>
#include <hip/hip_bf16.h>
#include <math.h>

#define NPIX 4096
#define CH   256

// ---- ws float offsets ----
#define OFF_XT   0u          // [2][4096][256] f32 (residual, lives until 2nd aggc2)
#define OFF_Y    2097152u    // [2][4096][256] f32 (fc out; later xnew)
#define OFF_E    4194304u    // [2][4096][256] f32 (edge feats; later xdTb bf16)
#define OFF_XBH  6291456u    // bf16 [2][4096][256] (x bf16; later xab = post-BN bf16)
#define OFF_CSRI 7340032u    // u16 pool, 2M entries (complement CSR indices)
#define OFF_HG   8388608u    // uint32 [2][4096][128] incidence bitmask
#define OFF_SQ   9437184u    // [8192] f32
#define OFF_PART 9445376u    // [128][512] f32 BN partials
#define OFF_BNSS 9510912u    // [512] f32
#define OFF_SPY  9511424u    // [2][64][256] colsum partials (y)
#define OFF_SY   9544192u    // [2][256]
#define OFF_SPE  9544704u    // [2][64][256] colsum partials (E)
#define OFF_SE   9577472u    // [2][256]
#define OFF_DEGC 9577984u    // [8192] int
#define OFF_CSRO 9586176u    // [8200] int
#define OFF_W3   9594376u    // bf16 [9][256][256] conv weights (tap-major, oc, c)
#define OFF_WFC  9889288u    // bf16 [256][256] fc weights
#define OFF_WOUT 9905672u    // bf16 [512][256] out weights
// end: 9971208 floats = 39.9 MB

typedef __attribute__((ext_vector_type(8))) short bf16x8;
typedef __attribute__((ext_vector_type(16))) float f32x16;

static __device__ __forceinline__ short f2b(float f) {
  __hip_bfloat16 h = __float2bfloat16(f);
  return *reinterpret_cast<short*>(&h);
}

// ---------- transpose x[b][c][n] -> xt[b][n][c] (f32) + xbh (bf16) ----------
__global__ void k_transpose(const float* __restrict__ x, float* __restrict__ xt,
                            __hip_bfloat16* __restrict__ xbh) {
  __shared__ float tile[32][33];
  const int b = blockIdx.z;
  const int n0 = blockIdx.x * 32, c0 = blockIdx.y * 32;
  const int tx = threadIdx.x, ty = threadIdx.y;
  const float* xb = x + (size_t)b * CH * NPIX;
  float* xtb = xt + (size_t)b * NPIX * CH;
  __hip_bfloat16* xhb = xbh + (size_t)b * NPIX * CH;
#pragma unroll
  for (int k = 0; k < 4; ++k)
    tile[ty + k * 8][tx] = xb[(c0 + ty + k * 8) * NPIX + n0 + tx];
  __syncthreads();
#pragma unroll
  for (int k = 0; k < 4; ++k) {
    const float v = tile[tx][ty + k * 8];
    const size_t o = (size_t)(n0 + ty + k * 8) * CH + c0 + tx;
    xtb[o] = v;
    xhb[o] = __float2bfloat16(v);
  }
}

// ---------- row squared norms (f32) ----------
__global__ void k_sq(const float* __restrict__ xt, float* __restrict__ sq) {
  const int row = blockIdx.x;  // 0..8191
  const int t = threadIdx.x;   // 64
  const float4 v = reinterpret_cast<const float4*>(xt + (size_t)row * CH)[t];
  float s = v.x * v.x + v.y * v.y + v.z * v.z + v.w * v.w;
#pragma unroll
  for (int off = 32; off; off >>= 1) s += __shfl_down(s, off);
  if (t == 0) sq[row] = s;
}

// ---------- Gram via bf16 MFMA, fused threshold -> incidence bitmask ----------
__global__ __launch_bounds__(256) void k_gram_mfma(const __hip_bfloat16* __restrict__ xbh,
                                                   const float* __restrict__ sq,
                                                   unsigned* __restrict__ hgbit) {
  const int b = blockIdx.z;
  const int i0 = blockIdx.y * 128, j0 = blockIdx.x * 128;
  const int t = threadIdx.x;
  const int lane = t & 63, wid = t >> 6;
  const int wm = wid >> 1, wn = wid & 1;
  const int c = lane & 31, h = lane >> 5;
  const short* base = (const short*)xbh + (size_t)b * NPIX * CH;
  const int ibase = i0 + wm * 64;
  const int jbase = j0 + wn * 64;

  f32x16 acc[2][2];
#pragma unroll
  for (int m = 0; m < 2; ++m)
#pragma unroll
    for (int n = 0; n < 2; ++n)
#pragma unroll
      for (int r = 0; r < 16; ++r) acc[m][n][r] = 0.f;

  const short* pa0 = base + (size_t)(ibase + c) * CH + h * 8;
  const short* pa1 = pa0 + 32 * CH;
  const short* pb0 = base + (size_t)(jbase + c) * CH + h * 8;
  const short* pb1 = pb0 + 32 * CH;

  for (int k0 = 0; k0 < CH; k0 += 16) {
    const bf16x8 a0 = *(const bf16x8*)(pa0 + k0);
    const bf16x8 a1 = *(const bf16x8*)(pa1 + k0);
    const bf16x8 b0 = *(const bf16x8*)(pb0 + k0);
    const bf16x8 b1 = *(const bf16x8*)(pb1 + k0);
    acc[0][0] = __builtin_amdgcn_mfma_f32_32x32x16_bf16(a0, b0, acc[0][0], 0, 0, 0);
    acc[0][1] = __builtin_amdgcn_mfma_f32_32x32x16_bf16(a0, b1, acc[0][1], 0, 0, 0);
    acc[1][0] = __builtin_amdgcn_mfma_f32_32x32x16_bf16(a1, b0, acc[1][0], 0, 0, 0);
    acc[1][1] = __builtin_amdgcn_mfma_f32_32x32x16_bf16(a1, b1, acc[1][1], 0, 0, 0);
  }

  const int sqb = b * NPIX;
#pragma unroll
  for (int m = 0; m < 2; ++m) {
    float4 sqa[4];
#pragma unroll
    for (int q = 0; q < 4; ++q)
      sqa[q] = *(const float4*)(sq + sqb + ibase + m * 32 + q * 8 + 4 * h);
#pragma unroll
    for (int n = 0; n < 2; ++n) {
      const float sj = sq[sqb + jbase + n * 32 + c];
      const int wj = (jbase + n * 32) >> 5;
#pragma unroll
      for (int q = 0; q < 4; ++q) {
        const float sqq[4] = {sqa[q].x, sqa[q].y, sqa[q].z, sqa[q].w};
#pragma unroll
        for (int rr = 0; rr < 4; ++rr) {
          const int reg = q * 4 + rr;
          const float d2 = sqq[rr] + sj - 2.f * acc[m][n][reg];
          const unsigned long long bal = __ballot(d2 < 100.f);
          if ((lane & 31) == reg) {
            const int row = ibase + m * 32 + rr + 8 * q + 4 * h;
            const unsigned wd = h ? (unsigned)(bal >> 32) : (unsigned)bal;
            hgbit[(size_t)(sqb + row) * 128 + wj] = wd;
          }
        }
      }
    }
  }
}

// ---------- complement degree per row ----------
__global__ void k_deg(const unsigned* __restrict__ hg, int* __restrict__ degc) {
  const int row = blockIdx.x, l = threadIdx.x;  // 64 thr
  const unsigned w0 = hg[(size_t)row * 128 + l * 2];
  const unsigned w1 = hg[(size_t)row * 128 + l * 2 + 1];
  int n = __popc(~w0) + __popc(~w1);
#pragma unroll
  for (int off = 32; off; off >>= 1) n += __shfl_down(n, off);
  if (l == 0) degc[row] = n;
}

// ---------- exclusive prefix sum of 8192 degrees (1 block) ----------
__global__ void k_scan(const int* __restrict__ degc, int* __restrict__ csroff) {
  __shared__ int ps[256];
  const int t = threadIdx.x;
  const int base = t * 32;
  int s = 0;
  for (int i = 0; i < 32; ++i) s += degc[base + i];
  ps[t] = s;
  __syncthreads();
  for (int d = 1; d < 256; d <<= 1) {
    const int v = (t >= d) ? ps[t - d] : 0;
    __syncthreads();
    ps[t] += v;
    __syncthreads();
  }
  int run = (t == 0) ? 0 : ps[t - 1];
  for (int i = 0; i < 32; ++i) { csroff[base + i] = run; run += degc[base + i]; }
  if (t == 255) csroff[8192] = run;
}

// ---------- fill CSR column indices (complement edges) ----------
__global__ void k_fill(const unsigned* __restrict__ hg, const int* __restrict__ csroff,
                       unsigned short* __restrict__ idx) {
  const int row = blockIdx.x, l = threadIdx.x;  // 64 thr
  unsigned w0 = ~hg[(size_t)row * 128 + l * 2];
  unsigned w1 = ~hg[(size_t)row * 128 + l * 2 + 1];
  const int n = __popc(w0) + __popc(w1);
  int p = n;
#pragma unroll
  for (int d = 1; d < 64; d <<= 1) {
    const int v = __shfl_up(p, d);
    if (l >= d) p += v;
  }
  p -= n;
  int wpos = csroff[row] + p;
  int c0 = l * 64;
  while (w0) { const int bb = __ffs(w0) - 1; w0 &= w0 - 1; idx[wpos++] = (unsigned short)(c0 + bb); }
  c0 += 32;
  while (w1) { const int bb = __ffs(w1) - 1; w1 &= w1 - 1; idx[wpos++] = (unsigned short)(c0 + bb); }
}

// ---------- generic bf16 MFMA NT GEMM: C(f32) = A(MxK) * B(NxK)^T + bias ----------
// block = 256 thr = 4 waves; block tile M=128 (wave 32), N=64 (2x 32x32 tiles)
__global__ __launch_bounds__(256) void k_mfma_nt(const short* __restrict__ A,
                                                 const short* __restrict__ B,
                                                 float* __restrict__ C,
                                                 const float* __restrict__ bias,
                                                 int M, int N, int K, int biasRow,
                                                 int bStride, int cStride) {
  B += (size_t)blockIdx.z * bStride;
  C += (size_t)blockIdx.z * cStride;
  const int t = threadIdx.x, l = t & 63, wid = t >> 6;
  const int m0 = blockIdx.y * 128 + wid * 32, n0 = blockIdx.x * 64;
  const int col = l & 31, half = l >> 5;
  f32x16 acc[2];
#pragma unroll
  for (int nt = 0; nt < 2; ++nt)
#pragma unroll
    for (int r = 0; r < 16; ++r) acc[nt][r] = 0.f;
  const short* pa = A + (size_t)(m0 + col) * K + half * 8;
  const short* pb0 = B + (size_t)(n0 + col) * K + half * 8;
  const short* pb1 = pb0 + 32 * K;
  for (int k0 = 0; k0 < K; k0 += 16) {
    const bf16x8 a = *(const bf16x8*)(pa + k0);
    const bf16x8 b0 = *(const bf16x8*)(pb0 + k0);
    const bf16x8 b1 = *(const bf16x8*)(pb1 + k0);
    acc[0] = __builtin_amdgcn_mfma_f32_32x32x16_bf16(a, b0, acc[0], 0, 0, 0);
    acc[1] = __builtin_amdgcn_mfma_f32_32x32x16_bf16(a, b1, acc[1], 0, 0, 0);
  }
#pragma unroll
  for (int nt = 0; nt < 2; ++nt) {
#pragma unroll
    for (int q = 0; q < 4; ++q)
#pragma unroll
      for (int rr = 0; rr < 4; ++rr) {
        const int reg = q * 4 + rr;
        const int row = m0 + rr + 8 * q + 4 * half;
        const int cc = n0 + nt * 32 + col;
        C[(size_t)row * N + cc] = acc[nt][reg] + (biasRow ? bias[row] : bias[cc]);
      }
  }
}

// ---------- column-sum partials ----------
__global__ void k_colsum(const float* __restrict__ src, float* __restrict__ Sp) {
  const int b = blockIdx.y, chunk = blockIdx.x, t = threadIdx.x;  // 64x2 blocks
  const float* p = src + ((size_t)b * NPIX + chunk * 64) * CH;
  float s = 0.f;
  for (int r = 0; r < 64; ++r) s += p[r * CH + t];
  Sp[((size_t)b * 64 + chunk) * CH + t] = s;
}

__global__ void k_colfin(const float* __restrict__ Sp, float* __restrict__ S) {
  const int b = blockIdx.x, t = threadIdx.x;
  float s = 0.f;
#pragma unroll
  for (int i = 0; i < 64; ++i) s += Sp[((size_t)b * 64 + i) * CH + t];
  S[b * CH + t] = s;
}

// ---------- complement mean-aggregation via CSR ----------
__global__ void k_aggc2(const int* __restrict__ csroff, const unsigned short* __restrict__ idx,
                        const float* __restrict__ src, const float* __restrict__ S,
                        const float* __restrict__ resid, float* __restrict__ dst) {
  const int row = blockIdx.x;  // b*4096 + i
  const int b = row >> 12;
  const int t = threadIdx.x;   // 256
  const int o0 = csroff[row], o1 = csroff[row + 1];
  const float* sb = src + (size_t)b * NPIX * CH;
  float a0 = 0.f, a1 = 0.f, a2 = 0.f, a3 = 0.f;
  int e = o0;
  for (; e + 4 <= o1; e += 4) {
    const int j0 = idx[e], j1 = idx[e + 1], j2 = idx[e + 2], j3 = idx[e + 3];
    a0 += sb[j0 * CH + t];
    a1 += sb[j1 * CH + t];
    a2 += sb[j2 * CH + t];
    a3 += sb[j3 * CH + t];
  }
  for (; e < o1; ++e) a0 += sb[(int)idx[e] * CH + t];
  const int nd = o1 - o0;
  float r = (nd >= NPIX) ? 0.f
          : (S[b * CH + t] - (a0 + a1 + a2 + a3)) / (float)(NPIX - nd);
  if (resid) r += resid[(size_t)row * CH + t];
  dst[(size_t)row * CH + t] = r;
}

// ---------- BN statistics ----------
__global__ void k_bnstat(const float* __restrict__ xn, float* __restrict__ part) {
  const int t = threadIdx.x, blk = blockIdx.x;  // 128 blocks x 64 rows
  float s = 0.f, ss = 0.f;
  const float* p = xn + (size_t)blk * 64 * CH;
  for (int r = 0; r < 64; ++r) {
    const float v = p[r * CH + t];
    s += v; ss += v * v;
  }
  part[blk * 512 + t] = s;
  part[blk * 512 + 256 + t] = ss;
}

__global__ void k_bnfin(const float* __restrict__ part, const float* __restrict__ gamma,
                        const float* __restrict__ beta, float* __restrict__ bnss) {
  const int t = threadIdx.x;  // 256
  float s = 0.f, ss = 0.f;
  for (int i = 0; i < 128; ++i) { s += part[i * 512 + t]; ss += part[i * 512 + 256 + t]; }
  const float mean = s * (1.f / 8192.f);
  const float var = ss * (1.f / 8192.f) - mean * mean;
  const float inv = rsqrtf(var + 1e-5f);
  const float sc = gamma[t] * inv;
  bnss[t] = sc;
  bnss[256 + t] = beta[t] - mean * sc;
}

// ---------- BN apply + SiLU (elementwise, pixel-major) -> bf16 xab[b][n][c] ----------
__global__ void k_bnapply2(const float* __restrict__ y, const float* __restrict__ bnss,
                           short* __restrict__ xab) {
  const int i = blockIdx.x * 256 + threadIdx.x;  // 524288 float4 groups
  const float4 v = reinterpret_cast<const float4*>(y)[i];
  const int c0 = (i & 63) * 4;
  const float4 sc = *(const float4*)(bnss + c0);
  const float4 sh = *(const float4*)(bnss + 256 + c0);
  const float u0 = v.x * sc.x + sh.x;
  const float u1 = v.y * sc.y + sh.y;
  const float u2 = v.z * sc.z + sh.z;
  const float u3 = v.w * sc.w + sh.w;
  short4 o;
  o.x = f2b(u0 / (1.f + expf(-u0)));
  o.y = f2b(u1 / (1.f + expf(-u1)));
  o.z = f2b(u2 / (1.f + expf(-u2)));
  o.w = f2b(u3 / (1.f + expf(-u3)));
  reinterpret_cast<short4*>(xab)[i] = o;
}

// ---------- weight converts ----------
__global__ void k_wcvt(const float* __restrict__ src, short* __restrict__ dst, int n) {
  const int i = blockIdx.x * 256 + threadIdx.x;
  if (i < n) dst[i] = f2b(src[i]);
}

// dw[oc][c][kh][kw] -> w3[tap][oc][c] bf16
__global__ void k_w3(const float* __restrict__ dw, short* __restrict__ w3) {
  const int i = blockIdx.x * 256 + threadIdx.x;  // 589824
  const int oc = i / 2304;
  const int rem = i % 2304;       // c*9 + tap
  const int c = rem / 9, tap = rem % 9;
  w3[((size_t)tap * 256 + oc) * 256 + c] = f2b(dw[i]);
}

// ---------- 3x3 stride-2 conv via direct MFMA (tap-decomposed NT GEMM) ----------
// one wave per block; wave tile: M=32 (ow row of one oh), N=64 oc (2 tiles)
__global__ __launch_bounds__(64) void k_conv3(const short* __restrict__ xab,
                                              const short* __restrict__ w3,
                                              const float* __restrict__ db,
                                              short* __restrict__ xdTb) {
  const int ocg = blockIdx.x;  // 0..3 (64 oc each)
  const int oh = blockIdx.y;   // 0..31
  const int b = blockIdx.z;
  const int l = threadIdx.x;
  const int col = l & 31, half = l >> 5;
  const short* xb = xab + (size_t)b * NPIX * CH;
  const bf16x8 zv = {0, 0, 0, 0, 0, 0, 0, 0};
  f32x16 acc[2];
#pragma unroll
  for (int nt = 0; nt < 2; ++nt)
#pragma unroll
    for (int r = 0; r < 16; ++r) acc[nt][r] = 0.f;

  for (int kh = 0; kh < 3; ++kh) {
    const int ih = 2 * oh + kh;
    if (ih >= 64) continue;
#pragma unroll
    for (int kw = 0; kw < 3; ++kw) {
      const int iw = 2 * col + kw;   // col = ow (A-row) here
      const bool ok = iw < 64;
      const short* pa = xb + (size_t)(ih * 64 + iw) * CH + half * 8;
      const short* pb = w3 + (size_t)((kh * 3 + kw) * 256 + ocg * 64 + col) * CH + half * 8;
#pragma unroll
      for (int ks = 0; ks < 16; ++ks) {
        const bf16x8 a = ok ? *(const bf16x8*)(pa + ks * 16) : zv;
        const bf16x8 b0 = *(const bf16x8*)(pb + ks * 16);
        const bf16x8 b1 = *(const bf16x8*)(pb + 32 * CH + ks * 16);
        acc[0] = __builtin_amdgcn_mfma_f32_32x32x16_bf16(a, b0, acc[0], 0, 0, 0);
        acc[1] = __builtin_amdgcn_mfma_f32_32x32x16_bf16(a, b1, acc[1], 0, 0, 0);
      }
    }
  }
#pragma unroll
  for (int nt = 0; nt < 2; ++nt) {
    const int oc = ocg * 64 + nt * 32 + col;
    const float bv = db[oc];
#pragma unroll
    for (int q = 0; q < 4; ++q)
#pragma unroll
      for (int rr = 0; rr < 4; ++rr) {
        const int reg = q * 4 + rr;
        const int ow = rr + 8 * q + 4 * half;
        xdTb[((size_t)b * 1024 + oh * 32 + ow) * CH + oc] = f2b(acc[nt][reg] + bv);
      }
  }
}

extern "C" void kernel_launch(void* const* d_in, const int* in_sizes, int n_in,
                              void* d_out, int out_size, void* d_ws, size_t ws_size,
                              hipStream_t stream) {
  const float* x     = (const float*)d_in[0];
  const float* fc_w  = (const float*)d_in[1];
  const float* fc_b  = (const float*)d_in[2];
  const float* gamma = (const float*)d_in[3];
  const float* beta  = (const float*)d_in[4];
  const float* dw    = (const float*)d_in[5];
  const float* db    = (const float*)d_in[6];
  const float* ow    = (const float*)d_in[7];
  const float* ob    = (const float*)d_in[8];

  float* ws   = (float*)d_ws;
  float* xt   = ws + OFF_XT;
  float* y    = ws + OFF_Y;
  float* E    = ws + OFF_E;
  float* sqv  = ws + OFF_SQ;
  float* part = ws + OFF_PART;
  float* bnss = ws + OFF_BNSS;
  unsigned* hg = (unsigned*)(ws + OFF_HG);
  __hip_bfloat16* xbh = (__hip_bfloat16*)(ws + OFF_XBH);
  short* xab  = (short*)(ws + OFF_XBH);      // aliases xbh (dead after fc GEMM)
  unsigned short* csri = (unsigned short*)(ws + OFF_CSRI);
  short* xdTb = (short*)(ws + OFF_E);        // aliases E (dead after 2nd aggc2)
  short* w3b  = (short*)(ws + OFF_W3);
  short* wfcb = (short*)(ws + OFF_WFC);
  short* woutb= (short*)(ws + OFF_WOUT);
  float* Spy  = ws + OFF_SPY;
  float* Sy   = ws + OFF_SY;
  float* Spe  = ws + OFF_SPE;
  float* Se   = ws + OFF_SE;
  int*   degc = (int*)(ws + OFF_DEGC);
  int*   csro = (int*)(ws + OFF_CSRO);
  float* out  = (float*)d_out;

  k_transpose<<<dim3(128, 8, 2), dim3(32, 8), 0, stream>>>(x, xt, xbh);
  k_sq<<<8192, 64, 0, stream>>>(xt, sqv);
  k_wcvt<<<256, 256, 0, stream>>>(fc_w, wfcb, 65536);
  k_wcvt<<<512, 256, 0, stream>>>(ow, woutb, 131072);
  k_w3<<<2304, 256, 0, stream>>>(dw, w3b);
  k_gram_mfma<<<dim3(32, 32, 2), 256, 0, stream>>>(xbh, sqv, hg);
  // y = xf @ fc_w^T + fc_b : M=8192 N=256 K=256 (while xbh alive)
  k_mfma_nt<<<dim3(4, 64, 1), 256, 0, stream>>>((const short*)xbh, wfcb, y, fc_b,
                                                8192, 256, 256, 0, 0, 0);
  // complement CSR
  k_deg<<<8192, 64, 0, stream>>>(hg, degc);
  k_scan<<<1, 256, 0, stream>>>(degc, csro);
  k_fill<<<8192, 64, 0, stream>>>(hg, csro, csri);
  // vertex -> edge
  k_colsum<<<dim3(64, 2), 256, 0, stream>>>(y, Spy);
  k_colfin<<<2, 256, 0, stream>>>(Spy, Sy);
  k_aggc2<<<8192, 256, 0, stream>>>(csro, csri, y, Sy, nullptr, E);
  // edge -> vertex + residual
  k_colsum<<<dim3(64, 2), 256, 0, stream>>>(E, Spe);
  k_colfin<<<2, 256, 0, stream>>>(Spe, Se);
  k_aggc2<<<8192, 256, 0, stream>>>(csro, csri, E, Se, xt, y);
  // BN + SiLU -> bf16 pixel-major
  k_bnstat<<<128, 256, 0, stream>>>(y, part);
  k_bnfin<<<1, 256, 0, stream>>>(part, gamma, beta, bnss);
  k_bnapply2<<<2048, 256, 0, stream>>>(y, bnss, xab);
  // 3x3 s2 conv (MFMA) -> bf16 [b][px][oc]
  k_conv3<<<dim3(4, 32, 2), 64, 0, stream>>>(xab, w3b, db, xdTb);
  // out = out_w @ xdT^T + out_b : per batch M=512 N=1024 K=256 (row bias)
  k_mfma_nt<<<dim3(16, 4, 2), 256, 0, stream>>>(woutb, xdTb, out, ob,
                                                512, 1024, 256, 1,
                                                1024 * 256, 512 * 1024);
}

// Round 5
// 349.346 us; speedup vs baseline: 21.6409x; 1.1571x over previous
//
#include <hip/hip_runtime.h>
#include <hip/hip_bf16.h>
#include <math.h>

#define NPIX 4096
#define CH   256

// ---- ws float offsets ----
#define OFF_XT   0u          // [2][4096][256] f32 residual (lives until hgemm#2)
#define OFF_Y    2097152u    // [2][4096][256] f32 v (hgemm#2 out -> BN)
#define OFF_E    4194304u    // [2][4096][256] f32 E (hgemm#1 out); later xdTb bf16
#define OFF_XBH  6291456u    // bf16 [2][4096][256] x bf16; later xab post-BN bf16
#define OFF_TB   7340032u    // bf16 [2][256][4096] yT; later ET
#define OFF_HG   8388608u    // uint32 [2][4096][128] incidence bitmask
#define OFF_SQ   9437184u    // [8192] f32
#define OFF_PART 9445376u    // [128][512] f32 BN partials
#define OFF_BNSS 9510912u    // [512] f32
#define OFF_DEG  9511424u    // [8192] int (direct degree)
#define OFF_W3   9519616u    // bf16 [9][256][256]
#define OFF_WFC  9814528u    // bf16 [256][256]
#define OFF_WOUT 9847296u    // bf16 [512][256]
// end: 9912832 floats = 39.7 MB

typedef __attribute__((ext_vector_type(8))) short bf16x8;
typedef __attribute__((ext_vector_type(16))) float f32x16;

static __device__ __forceinline__ short f2b(float f) {
  __hip_bfloat16 h = __float2bfloat16(f);
  return *reinterpret_cast<short*>(&h);
}

// expand 8 incidence bits -> 8 bf16 {0,1}: bit i -> element i
static __device__ __forceinline__ bf16x8 bits2bf(unsigned v) {
  union { unsigned u[4]; bf16x8 h; } r;
#pragma unroll
  for (int k = 0; k < 4; ++k) {
    const unsigned s = v >> (2 * k);
    r.u[k] = ((s & 1u) | ((s & 2u) << 15)) * 0x3F80u;
  }
  return r.h;
}

// ---------- transpose x[b][c][n] -> xt[b][n][c] (f32) + xbh (bf16) ----------
__global__ void k_transpose(const float* __restrict__ x, float* __restrict__ xt,
                            __hip_bfloat16* __restrict__ xbh) {
  __shared__ float tile[32][33];
  const int b = blockIdx.z;
  const int n0 = blockIdx.x * 32, c0 = blockIdx.y * 32;
  const int tx = threadIdx.x, ty = threadIdx.y;
  const float* xb = x + (size_t)b * CH * NPIX;
  float* xtb = xt + (size_t)b * NPIX * CH;
  __hip_bfloat16* xhb = xbh + (size_t)b * NPIX * CH;
#pragma unroll
  for (int k = 0; k < 4; ++k)
    tile[ty + k * 8][tx] = xb[(c0 + ty + k * 8) * NPIX + n0 + tx];
  __syncthreads();
#pragma unroll
  for (int k = 0; k < 4; ++k) {
    const float v = tile[tx][ty + k * 8];
    const size_t o = (size_t)(n0 + ty + k * 8) * CH + c0 + tx;
    xtb[o] = v;
    xhb[o] = __float2bfloat16(v);
  }
}

// ---------- row squared norms (f32) ----------
__global__ void k_sq(const float* __restrict__ xt, float* __restrict__ sq) {
  const int row = blockIdx.x;  // 0..8191
  const int t = threadIdx.x;   // 64
  const float4 v = reinterpret_cast<const float4*>(xt + (size_t)row * CH)[t];
  float s = v.x * v.x + v.y * v.y + v.z * v.z + v.w * v.w;
#pragma unroll
  for (int off = 32; off; off >>= 1) s += __shfl_down(s, off);
  if (t == 0) sq[row] = s;
}

// ---------- Gram via bf16 MFMA, fused threshold -> incidence bitmask ----------
__global__ __launch_bounds__(256) void k_gram_mfma(const __hip_bfloat16* __restrict__ xbh,
                                                   const float* __restrict__ sq,
                                                   unsigned* __restrict__ hgbit) {
  const int b = blockIdx.z;
  const int i0 = blockIdx.y * 128, j0 = blockIdx.x * 128;
  const int t = threadIdx.x;
  const int lane = t & 63, wid = t >> 6;
  const int wm = wid >> 1, wn = wid & 1;
  const int c = lane & 31, h = lane >> 5;
  const short* base = (const short*)xbh + (size_t)b * NPIX * CH;
  const int ibase = i0 + wm * 64;
  const int jbase = j0 + wn * 64;

  f32x16 acc[2][2];
#pragma unroll
  for (int m = 0; m < 2; ++m)
#pragma unroll
    for (int n = 0; n < 2; ++n)
#pragma unroll
      for (int r = 0; r < 16; ++r) acc[m][n][r] = 0.f;

  const short* pa0 = base + (size_t)(ibase + c) * CH + h * 8;
  const short* pa1 = pa0 + 32 * CH;
  const short* pb0 = base + (size_t)(jbase + c) * CH + h * 8;
  const short* pb1 = pb0 + 32 * CH;

  for (int k0 = 0; k0 < CH; k0 += 16) {
    const bf16x8 a0 = *(const bf16x8*)(pa0 + k0);
    const bf16x8 a1 = *(const bf16x8*)(pa1 + k0);
    const bf16x8 b0 = *(const bf16x8*)(pb0 + k0);
    const bf16x8 b1 = *(const bf16x8*)(pb1 + k0);
    acc[0][0] = __builtin_amdgcn_mfma_f32_32x32x16_bf16(a0, b0, acc[0][0], 0, 0, 0);
    acc[0][1] = __builtin_amdgcn_mfma_f32_32x32x16_bf16(a0, b1, acc[0][1], 0, 0, 0);
    acc[1][0] = __builtin_amdgcn_mfma_f32_32x32x16_bf16(a1, b0, acc[1][0], 0, 0, 0);
    acc[1][1] = __builtin_amdgcn_mfma_f32_32x32x16_bf16(a1, b1, acc[1][1], 0, 0, 0);
  }

  const int sqb = b * NPIX;
#pragma unroll
  for (int m = 0; m < 2; ++m) {
    float4 sqa[4];
#pragma unroll
    for (int q = 0; q < 4; ++q)
      sqa[q] = *(const float4*)(sq + sqb + ibase + m * 32 + q * 8 + 4 * h);
#pragma unroll
    for (int n = 0; n < 2; ++n) {
      const float sj = sq[sqb + jbase + n * 32 + c];
      const int wj = (jbase + n * 32) >> 5;
#pragma unroll
      for (int q = 0; q < 4; ++q) {
        const float sqq[4] = {sqa[q].x, sqa[q].y, sqa[q].z, sqa[q].w};
#pragma unroll
        for (int rr = 0; rr < 4; ++rr) {
          const int reg = q * 4 + rr;
          const float d2 = sqq[rr] + sj - 2.f * acc[m][n][reg];
          const unsigned long long bal = __ballot(d2 < 100.f);
          if ((lane & 31) == reg) {
            const int row = ibase + m * 32 + rr + 8 * q + 4 * h;
            const unsigned wd = h ? (unsigned)(bal >> 32) : (unsigned)bal;
            hgbit[(size_t)(sqb + row) * 128 + wj] = wd;
          }
        }
      }
    }
  }
}

// ---------- direct degree per row ----------
__global__ void k_deg(const unsigned* __restrict__ hg, int* __restrict__ deg) {
  const int row = blockIdx.x, l = threadIdx.x;  // 64 thr
  const unsigned w0 = hg[(size_t)row * 128 + l * 2];
  const unsigned w1 = hg[(size_t)row * 128 + l * 2 + 1];
  int n = __popc(w0) + __popc(w1);
#pragma unroll
  for (int off = 32; off; off >>= 1) n += __shfl_down(n, off);
  if (l == 0) deg[row] = n;
}

// ---------- H @ src via bit-expanded MFMA: dst[i][c] = (sum_j H[i][j] srcT[c][j])/deg[i] ----------
// one wave per block; wave tile M=64 (i), N=128 (c); K=4096 (j)
__global__ __launch_bounds__(64) void k_hgemm(const unsigned* __restrict__ hg,
                                              const short* __restrict__ srcT,
                                              const int* __restrict__ deg,
                                              const float* __restrict__ resid,
                                              float* __restrict__ dst) {
  const int b = blockIdx.z;
  const int n0 = blockIdx.x * 128;   // channel base
  const int m0 = blockIdx.y * 64;    // node-row base
  const int l = threadIdx.x;
  const int col = l & 31, half = l >> 5;
  const unsigned char* hb = (const unsigned char*)hg + (size_t)b * NPIX * 512;
  const short* Bt = srcT + (size_t)b * CH * NPIX;

  f32x16 acc[2][4];
#pragma unroll
  for (int mt = 0; mt < 2; ++mt)
#pragma unroll
    for (int nt = 0; nt < 4; ++nt)
#pragma unroll
      for (int r = 0; r < 16; ++r) acc[mt][nt][r] = 0.f;

  const unsigned char* pA0 = hb + (size_t)(m0 + col) * 512;
  const unsigned char* pA1 = pA0 + 32 * 512;
  const short* pB0 = Bt + (size_t)(n0 + col) * NPIX + half * 8;
  const int sh = half * 8;

  for (int k0 = 0; k0 < NPIX; k0 += 32) {
    const unsigned wa0 = *(const unsigned*)(pA0 + (k0 >> 3));
    const unsigned wa1 = *(const unsigned*)(pA1 + (k0 >> 3));
#pragma unroll
    for (int s = 0; s < 2; ++s) {       // two k-steps of 16
      const int kk = k0 + s * 16;
      const bf16x8 a0 = bits2bf((wa0 >> (sh + s * 16)) & 0xFFu);
      const bf16x8 a1 = bits2bf((wa1 >> (sh + s * 16)) & 0xFFu);
#pragma unroll
      for (int nt = 0; nt < 4; ++nt) {
        const bf16x8 bf = *(const bf16x8*)(pB0 + (size_t)nt * 32 * NPIX + kk);
        acc[0][nt] = __builtin_amdgcn_mfma_f32_32x32x16_bf16(a0, bf, acc[0][nt], 0, 0, 0);
        acc[1][nt] = __builtin_amdgcn_mfma_f32_32x32x16_bf16(a1, bf, acc[1][nt], 0, 0, 0);
      }
    }
  }

#pragma unroll
  for (int mt = 0; mt < 2; ++mt) {
#pragma unroll
    for (int q = 0; q < 4; ++q)
#pragma unroll
      for (int rr = 0; rr < 4; ++rr) {
        const int reg = q * 4 + rr;
        const int r = m0 + mt * 32 + rr + 8 * q + 4 * half;
        const float dinv = 1.0f / (float)deg[b * NPIX + r];
#pragma unroll
        for (int nt = 0; nt < 4; ++nt) {
          const int cc = n0 + nt * 32 + col;
          float v = acc[mt][nt][reg] * dinv;
          if (resid) v += resid[((size_t)(b * NPIX + r)) * CH + cc];
          dst[((size_t)(b * NPIX + r)) * CH + cc] = v;
        }
      }
  }
}

// ---------- transpose f32 [b][n][c] -> bf16 [b][c][n] ----------
__global__ void k_t2b(const float* __restrict__ src, short* __restrict__ dst) {
  __shared__ float tile[32][33];
  const int b = blockIdx.z;
  const int n0 = blockIdx.x * 32, c0 = blockIdx.y * 32;
  const int tx = threadIdx.x, ty = threadIdx.y;
  const float* sb = src + (size_t)b * NPIX * CH;
  short* db = dst + (size_t)b * CH * NPIX;
#pragma unroll
  for (int k = 0; k < 4; ++k)
    tile[ty + k * 8][tx] = sb[(size_t)(n0 + ty + k * 8) * CH + c0 + tx];
  __syncthreads();
#pragma unroll
  for (int k = 0; k < 4; ++k)
    db[(size_t)(c0 + ty + k * 8) * NPIX + n0 + tx] = f2b(tile[tx][ty + k * 8]);
}

// ---------- bf16 MFMA NT GEMM, f32 out + row bias ----------
__global__ __launch_bounds__(256) void k_mfma_nt(const short* __restrict__ A,
                                                 const short* __restrict__ B,
                                                 float* __restrict__ C,
                                                 const float* __restrict__ bias,
                                                 int N, int K,
                                                 int bStride, int cStride) {
  B += (size_t)blockIdx.z * bStride;
  C += (size_t)blockIdx.z * cStride;
  const int t = threadIdx.x, l = t & 63, wid = t >> 6;
  const int m0 = blockIdx.y * 128 + wid * 32, n0 = blockIdx.x * 64;
  const int col = l & 31, half = l >> 5;
  f32x16 acc[2];
#pragma unroll
  for (int nt = 0; nt < 2; ++nt)
#pragma unroll
    for (int r = 0; r < 16; ++r) acc[nt][r] = 0.f;
  const short* pa = A + (size_t)(m0 + col) * K + half * 8;
  const short* pb0 = B + (size_t)(n0 + col) * K + half * 8;
  const short* pb1 = pb0 + 32 * K;
  for (int k0 = 0; k0 < K; k0 += 16) {
    const bf16x8 a = *(const bf16x8*)(pa + k0);
    const bf16x8 b0 = *(const bf16x8*)(pb0 + k0);
    const bf16x8 b1 = *(const bf16x8*)(pb1 + k0);
    acc[0] = __builtin_amdgcn_mfma_f32_32x32x16_bf16(a, b0, acc[0], 0, 0, 0);
    acc[1] = __builtin_amdgcn_mfma_f32_32x32x16_bf16(a, b1, acc[1], 0, 0, 0);
  }
#pragma unroll
  for (int nt = 0; nt < 2; ++nt) {
#pragma unroll
    for (int q = 0; q < 4; ++q)
#pragma unroll
      for (int rr = 0; rr < 4; ++rr) {
        const int reg = q * 4 + rr;
        const int row = m0 + rr + 8 * q + 4 * half;
        const int cc = n0 + nt * 32 + col;
        C[(size_t)row * N + cc] = acc[nt][reg] + bias[row];
      }
  }
}

// ---------- bf16 MFMA NT GEMM, bf16 out + row bias (fc -> yT) ----------
__global__ __launch_bounds__(256) void k_mfma_ntb(const short* __restrict__ A,
                                                  const short* __restrict__ B,
                                                  short* __restrict__ C,
                                                  const float* __restrict__ bias,
                                                  int N, int K,
                                                  int bStride, int cStride) {
  B += (size_t)blockIdx.z * bStride;
  C += (size_t)blockIdx.z * cStride;
  const int t = threadIdx.x, l = t & 63, wid = t >> 6;
  const int m0 = blockIdx.y * 128 + wid * 32, n0 = blockIdx.x * 64;
  const int col = l & 31, half = l >> 5;
  f32x16 acc[2];
#pragma unroll
  for (int nt = 0; nt < 2; ++nt)
#pragma unroll
    for (int r = 0; r < 16; ++r) acc[nt][r] = 0.f;
  const short* pa = A + (size_t)(m0 + col) * K + half * 8;
  const short* pb0 = B + (size_t)(n0 + col) * K + half * 8;
  const short* pb1 = pb0 + 32 * K;
  for (int k0 = 0; k0 < K; k0 += 16) {
    const bf16x8 a = *(const bf16x8*)(pa + k0);
    const bf16x8 b0 = *(const bf16x8*)(pb0 + k0);
    const bf16x8 b1 = *(const bf16x8*)(pb1 + k0);
    acc[0] = __builtin_amdgcn_mfma_f32_32x32x16_bf16(a, b0, acc[0], 0, 0, 0);
    acc[1] = __builtin_amdgcn_mfma_f32_32x32x16_bf16(a, b1, acc[1], 0, 0, 0);
  }
#pragma unroll
  for (int nt = 0; nt < 2; ++nt) {
#pragma unroll
    for (int q = 0; q < 4; ++q)
#pragma unroll
      for (int rr = 0; rr < 4; ++rr) {
        const int reg = q * 4 + rr;
        const int row = m0 + rr + 8 * q + 4 * half;
        const int cc = n0 + nt * 32 + col;
        C[(size_t)row * N + cc] = f2b(acc[nt][reg] + bias[row]);
      }
  }
}

// ---------- BN statistics ----------
__global__ void k_bnstat(const float* __restrict__ xn, float* __restrict__ part) {
  const int t = threadIdx.x, blk = blockIdx.x;  // 128 blocks x 64 rows
  float s = 0.f, ss = 0.f;
  const float* p = xn + (size_t)blk * 64 * CH;
  for (int r = 0; r < 64; ++r) {
    const float v = p[r * CH + t];
    s += v; ss += v * v;
  }
  part[blk * 512 + t] = s;
  part[blk * 512 + 256 + t] = ss;
}

__global__ void k_bnfin(const float* __restrict__ part, const float* __restrict__ gamma,
                        const float* __restrict__ beta, float* __restrict__ bnss) {
  const int t = threadIdx.x;  // 256
  float s = 0.f, ss = 0.f;
  for (int i = 0; i < 128; ++i) { s += part[i * 512 + t]; ss += part[i * 512 + 256 + t]; }
  const float mean = s * (1.f / 8192.f);
  const float var = ss * (1.f / 8192.f) - mean * mean;
  const float inv = rsqrtf(var + 1e-5f);
  const float sc = gamma[t] * inv;
  bnss[t] = sc;
  bnss[256 + t] = beta[t] - mean * sc;
}

// ---------- BN apply + SiLU (elementwise, pixel-major) -> bf16 xab[b][n][c] ----------
__global__ void k_bnapply2(const float* __restrict__ y, const float* __restrict__ bnss,
                           short* __restrict__ xab) {
  const int i = blockIdx.x * 256 + threadIdx.x;  // 524288 float4 groups
  const float4 v = reinterpret_cast<const float4*>(y)[i];
  const int c0 = (i & 63) * 4;
  const float4 sc = *(const float4*)(bnss + c0);
  const float4 sh = *(const float4*)(bnss + 256 + c0);
  const float u0 = v.x * sc.x + sh.x;
  const float u1 = v.y * sc.y + sh.y;
  const float u2 = v.z * sc.z + sh.z;
  const float u3 = v.w * sc.w + sh.w;
  short4 o;
  o.x = f2b(u0 / (1.f + expf(-u0)));
  o.y = f2b(u1 / (1.f + expf(-u1)));
  o.z = f2b(u2 / (1.f + expf(-u2)));
  o.w = f2b(u3 / (1.f + expf(-u3)));
  reinterpret_cast<short4*>(xab)[i] = o;
}

// ---------- weight converts ----------
__global__ void k_wcvt(const float* __restrict__ src, short* __restrict__ dst, int n) {
  const int i = blockIdx.x * 256 + threadIdx.x;
  if (i < n) dst[i] = f2b(src[i]);
}

// dw[oc][c][kh][kw] -> w3[tap][oc][c] bf16
__global__ void k_w3(const float* __restrict__ dw, short* __restrict__ w3) {
  const int i = blockIdx.x * 256 + threadIdx.x;  // 589824
  const int oc = i / 2304;
  const int rem = i % 2304;       // c*9 + tap
  const int c = rem / 9, tap = rem % 9;
  w3[((size_t)tap * 256 + oc) * 256 + c] = f2b(dw[i]);
}

// ---------- 3x3 stride-2 conv via direct MFMA ----------
__global__ __launch_bounds__(64) void k_conv3(const short* __restrict__ xab,
                                              const short* __restrict__ w3,
                                              const float* __restrict__ db,
                                              short* __restrict__ xdTb) {
  const int ocg = blockIdx.x;  // 0..3 (64 oc each)
  const int oh = blockIdx.y;   // 0..31
  const int b = blockIdx.z;
  const int l = threadIdx.x;
  const int col = l & 31, half = l >> 5;
  const short* xb = xab + (size_t)b * NPIX * CH;
  const bf16x8 zv = {0, 0, 0, 0, 0, 0, 0, 0};
  f32x16 acc[2];
#pragma unroll
  for (int nt = 0; nt < 2; ++nt)
#pragma unroll
    for (int r = 0; r < 16; ++r) acc[nt][r] = 0.f;

  for (int kh = 0; kh < 3; ++kh) {
    const int ih = 2 * oh + kh;
    if (ih >= 64) continue;
#pragma unroll
    for (int kw = 0; kw < 3; ++kw) {
      const int iw = 2 * col + kw;
      const bool ok = iw < 64;
      const short* pa = xb + (size_t)(ih * 64 + iw) * CH + half * 8;
      const short* pb = w3 + (size_t)((kh * 3 + kw) * 256 + ocg * 64 + col) * CH + half * 8;
#pragma unroll
      for (int ks = 0; ks < 16; ++ks) {
        const bf16x8 a = ok ? *(const bf16x8*)(pa + ks * 16) : zv;
        const bf16x8 b0 = *(const bf16x8*)(pb + ks * 16);
        const bf16x8 b1 = *(const bf16x8*)(pb + 32 * CH + ks * 16);
        acc[0] = __builtin_amdgcn_mfma_f32_32x32x16_bf16(a, b0, acc[0], 0, 0, 0);
        acc[1] = __builtin_amdgcn_mfma_f32_32x32x16_bf16(a, b1, acc[1], 0, 0, 0);
      }
    }
  }
#pragma unroll
  for (int nt = 0; nt < 2; ++nt) {
    const int oc = ocg * 64 + nt * 32 + col;
    const float bv = db[oc];
#pragma unroll
    for (int q = 0; q < 4; ++q)
#pragma unroll
      for (int rr = 0; rr < 4; ++rr) {
        const int reg = q * 4 + rr;
        const int ow = rr + 8 * q + 4 * half;
        xdTb[((size_t)b * 1024 + oh * 32 + ow) * CH + oc] = f2b(acc[nt][reg] + bv);
      }
  }
}

extern "C" void kernel_launch(void* const* d_in, const int* in_sizes, int n_in,
                              void* d_out, int out_size, void* d_ws, size_t ws_size,
                              hipStream_t stream) {
  const float* x     = (const float*)d_in[0];
  const float* fc_w  = (const float*)d_in[1];
  const float* fc_b  = (const float*)d_in[2];
  const float* gamma = (const float*)d_in[3];
  const float* beta  = (const float*)d_in[4];
  const float* dw    = (const float*)d_in[5];
  const float* db    = (const float*)d_in[6];
  const float* ow    = (const float*)d_in[7];
  const float* ob    = (const float*)d_in[8];

  float* ws   = (float*)d_ws;
  float* xt   = ws + OFF_XT;
  float* v    = ws + OFF_Y;
  float* E    = ws + OFF_E;
  float* sqv  = ws + OFF_SQ;
  float* part = ws + OFF_PART;
  float* bnss = ws + OFF_BNSS;
  unsigned* hg = (unsigned*)(ws + OFF_HG);
  __hip_bfloat16* xbh = (__hip_bfloat16*)(ws + OFF_XBH);
  short* xab  = (short*)(ws + OFF_XBH);   // aliases xbh (dead after fc+gram)
  short* tb   = (short*)(ws + OFF_TB);    // yT then ET
  short* xdTb = (short*)(ws + OFF_E);     // aliases E (dead after t2b)
  short* w3b  = (short*)(ws + OFF_W3);
  short* wfcb = (short*)(ws + OFF_WFC);
  short* woutb= (short*)(ws + OFF_WOUT);
  int*   deg  = (int*)(ws + OFF_DEG);
  float* out  = (float*)d_out;

  k_transpose<<<dim3(128, 8, 2), dim3(32, 8), 0, stream>>>(x, xt, xbh);
  k_sq<<<8192, 64, 0, stream>>>(xt, sqv);
  k_wcvt<<<256, 256, 0, stream>>>(fc_w, wfcb, 65536);
  k_wcvt<<<512, 256, 0, stream>>>(ow, woutb, 131072);
  k_w3<<<2304, 256, 0, stream>>>(dw, w3b);
  k_gram_mfma<<<dim3(32, 32, 2), 256, 0, stream>>>(xbh, sqv, hg);
  // yT = fc_w @ xf^T + fc_b (bf16 out): M=256, N=4096, K=256 per batch
  k_mfma_ntb<<<dim3(64, 2, 2), 256, 0, stream>>>(wfcb, (const short*)xbh, tb, fc_b,
                                                 4096, 256, NPIX * CH, CH * NPIX);
  k_deg<<<8192, 64, 0, stream>>>(hg, deg);
  // E = (H @ y)/deg
  k_hgemm<<<dim3(2, 64, 2), 64, 0, stream>>>(hg, tb, deg, nullptr, E);
  // ET bf16 (overwrites yT region)
  k_t2b<<<dim3(128, 8, 2), dim3(32, 8), 0, stream>>>(E, tb);
  // v = (H @ E)/deg + xf
  k_hgemm<<<dim3(2, 64, 2), 64, 0, stream>>>(hg, tb, deg, xt, v);
  // BN + SiLU -> bf16 pixel-major
  k_bnstat<<<128, 256, 0, stream>>>(v, part);
  k_bnfin<<<1, 256, 0, stream>>>(part, gamma, beta, bnss);
  k_bnapply2<<<2048, 256, 0, stream>>>(v, bnss, xab);
  // 3x3 s2 conv (MFMA) -> bf16 [b][px][oc]
  k_conv3<<<dim3(4, 32, 2), 64, 0, stream>>>(xab, w3b, db, xdTb);
  // out = out_w @ xdT^T + out_b : per batch M=512, N=1024, K=256 (row bias)
  k_mfma_nt<<<dim3(16, 4, 2), 256, 0, stream>>>(woutb, xdTb, out, ob,
                                                1024, 256, 1024 * 256, 512 * 1024);
}

// Round 6
// 219.484 us; speedup vs baseline: 34.4451x; 1.5917x over previous
//
#include <hip/hip_runtime.h>
#include <hip/hip_bf16.h>
#include <math.h>

#define NPIX 4096
#define CH   256

// ---- ws float offsets ----
#define OFF_XT   0u          // [2][4096][256] f32 residual (lives until hgemm_n)
#define OFF_Y    2097152u    // [2][4096][256] f32 v (hgemm_n out -> BN)
#define OFF_XBH  4194304u    // bf16 [2][4096][256] x bf16; later xab post-BN bf16
#define OFF_TBS  5242880u    // bf16 swizzled y^T [2][8][512][32][8]; later xdTb
#define OFF_TBS2 6291456u    // bf16 swizzled E^T [2][8][512][32][8]
#define OFF_HG   7340032u    // uint32 [2][4096][128] incidence bitmask
#define OFF_SQ   8388608u    // [8192] f32
#define OFF_PART 8396800u    // [128][512] f32 BN partials
#define OFF_BNSS 8462336u    // [512] f32
#define OFF_DINV 8462848u    // [8192] f32 1/deg
#define OFF_W3   8471040u    // bf16 [9][256][256]
#define OFF_WFC  8765952u    // bf16 [256][256]
#define OFF_WOUT 8798720u    // bf16 [512][256]
// end: 8864256 floats = 35.5 MB

typedef __attribute__((ext_vector_type(8))) short bf16x8;
typedef __attribute__((ext_vector_type(16))) float f32x16;

static __device__ __forceinline__ short f2b(float f) {
  __hip_bfloat16 h = __float2bfloat16(f);
  return *reinterpret_cast<short*>(&h);
}

// expand 8 incidence bits (byte) -> bf16x8 of {0,1}
static __device__ __forceinline__ bf16x8 byte2bf(unsigned byte) {
  union { unsigned u[4]; bf16x8 h; } r;
  r.u[0] = ((byte * 0x8001u) & 0x10001u) * 0x3F80u;
  r.u[1] = (((byte >> 2) * 0x8001u) & 0x10001u) * 0x3F80u;
  r.u[2] = (((byte >> 4) * 0x8001u) & 0x10001u) * 0x3F80u;
  r.u[3] = (((byte >> 6) * 0x8001u) & 0x10001u) * 0x3F80u;
  return r.h;
}

// ---------- transpose x[b][c][n] -> xt[b][n][c] (f32) + xbh (bf16) ----------
__global__ void k_transpose(const float* __restrict__ x, float* __restrict__ xt,
                            __hip_bfloat16* __restrict__ xbh) {
  __shared__ float tile[32][33];
  const int b = blockIdx.z;
  const int n0 = blockIdx.x * 32, c0 = blockIdx.y * 32;
  const int tx = threadIdx.x, ty = threadIdx.y;
  const float* xb = x + (size_t)b * CH * NPIX;
  float* xtb = xt + (size_t)b * NPIX * CH;
  __hip_bfloat16* xhb = xbh + (size_t)b * NPIX * CH;
#pragma unroll
  for (int k = 0; k < 4; ++k)
    tile[ty + k * 8][tx] = xb[(c0 + ty + k * 8) * NPIX + n0 + tx];
  __syncthreads();
#pragma unroll
  for (int k = 0; k < 4; ++k) {
    const float v = tile[tx][ty + k * 8];
    const size_t o = (size_t)(n0 + ty + k * 8) * CH + c0 + tx;
    xtb[o] = v;
    xhb[o] = __float2bfloat16(v);
  }
}

// ---------- row squared norms (f32) ----------
__global__ void k_sq(const float* __restrict__ xt, float* __restrict__ sq) {
  const int row = blockIdx.x;  // 0..8191
  const int t = threadIdx.x;   // 64
  const float4 v = reinterpret_cast<const float4*>(xt + (size_t)row * CH)[t];
  float s = v.x * v.x + v.y * v.y + v.z * v.z + v.w * v.w;
#pragma unroll
  for (int off = 32; off; off >>= 1) s += __shfl_down(s, off);
  if (t == 0) sq[row] = s;
}

// ---------- Gram via bf16 MFMA, fused threshold -> incidence bitmask ----------
__global__ __launch_bounds__(256) void k_gram_mfma(const __hip_bfloat16* __restrict__ xbh,
                                                   const float* __restrict__ sq,
                                                   unsigned* __restrict__ hgbit) {
  const int b = blockIdx.z;
  const int i0 = blockIdx.y * 128, j0 = blockIdx.x * 128;
  const int t = threadIdx.x;
  const int lane = t & 63, wid = t >> 6;
  const int wm = wid >> 1, wn = wid & 1;
  const int c = lane & 31, h = lane >> 5;
  const short* base = (const short*)xbh + (size_t)b * NPIX * CH;
  const int ibase = i0 + wm * 64;
  const int jbase = j0 + wn * 64;

  f32x16 acc[2][2];
#pragma unroll
  for (int m = 0; m < 2; ++m)
#pragma unroll
    for (int n = 0; n < 2; ++n)
#pragma unroll
      for (int r = 0; r < 16; ++r) acc[m][n][r] = 0.f;

  const short* pa0 = base + (size_t)(ibase + c) * CH + h * 8;
  const short* pa1 = pa0 + 32 * CH;
  const short* pb0 = base + (size_t)(jbase + c) * CH + h * 8;
  const short* pb1 = pb0 + 32 * CH;

  for (int k0 = 0; k0 < CH; k0 += 16) {
    const bf16x8 a0 = *(const bf16x8*)(pa0 + k0);
    const bf16x8 a1 = *(const bf16x8*)(pa1 + k0);
    const bf16x8 b0 = *(const bf16x8*)(pb0 + k0);
    const bf16x8 b1 = *(const bf16x8*)(pb1 + k0);
    acc[0][0] = __builtin_amdgcn_mfma_f32_32x32x16_bf16(a0, b0, acc[0][0], 0, 0, 0);
    acc[0][1] = __builtin_amdgcn_mfma_f32_32x32x16_bf16(a0, b1, acc[0][1], 0, 0, 0);
    acc[1][0] = __builtin_amdgcn_mfma_f32_32x32x16_bf16(a1, b0, acc[1][0], 0, 0, 0);
    acc[1][1] = __builtin_amdgcn_mfma_f32_32x32x16_bf16(a1, b1, acc[1][1], 0, 0, 0);
  }

  const int sqb = b * NPIX;
#pragma unroll
  for (int m = 0; m < 2; ++m) {
    float4 sqa[4];
#pragma unroll
    for (int q = 0; q < 4; ++q)
      sqa[q] = *(const float4*)(sq + sqb + ibase + m * 32 + q * 8 + 4 * h);
#pragma unroll
    for (int n = 0; n < 2; ++n) {
      const float sj = sq[sqb + jbase + n * 32 + c];
      const int wj = (jbase + n * 32) >> 5;
#pragma unroll
      for (int q = 0; q < 4; ++q) {
        const float sqq[4] = {sqa[q].x, sqa[q].y, sqa[q].z, sqa[q].w};
#pragma unroll
        for (int rr = 0; rr < 4; ++rr) {
          const int reg = q * 4 + rr;
          const float d2 = sqq[rr] + sj - 2.f * acc[m][n][reg];
          const unsigned long long bal = __ballot(d2 < 100.f);
          if ((lane & 31) == reg) {
            const int row = ibase + m * 32 + rr + 8 * q + 4 * h;
            const unsigned wd = h ? (unsigned)(bal >> 32) : (unsigned)bal;
            hgbit[(size_t)(sqb + row) * 128 + wj] = wd;
          }
        }
      }
    }
  }
}

// ---------- 1/deg per row ----------
__global__ void k_dinv(const unsigned* __restrict__ hg, float* __restrict__ dinvf) {
  const int row = blockIdx.x, l = threadIdx.x;  // 64 thr
  const unsigned w0 = hg[(size_t)row * 128 + l * 2];
  const unsigned w1 = hg[(size_t)row * 128 + l * 2 + 1];
  int n = __popc(w0) + __popc(w1);
#pragma unroll
  for (int off = 32; off; off >>= 1) n += __shfl_down(n, off);
  if (l == 0) dinvf[row] = 1.0f / (float)n;
}

// ---------- hgemm_t: E^T[c][n] = (sum_j y^T[c][j] H[n][j]) * dinv[n], swizzled bf16 out ----
// one wave per block; tile M=32 channels x N=32 nodes; K=4096
__global__ __launch_bounds__(64) void k_hgemm_t(const short* __restrict__ tbs,
                                                const unsigned* __restrict__ hg,
                                                const float* __restrict__ dinvf,
                                                short* __restrict__ tbs2) {
  const int b = blockIdx.z;
  const int n0 = blockIdx.x * 32;   // node tile
  const int m0 = blockIdx.y * 32;   // channel tile (cb = blockIdx.y)
  const int l = threadIdx.x;
  const int col = l & 31, half = l >> 5;
  const int sh8 = half * 8;

  f32x16 acc;
#pragma unroll
  for (int r = 0; r < 16; ++r) acc[r] = 0.f;

  const short* pa = tbs + ((size_t)b << 20) + ((size_t)blockIdx.y * 512 + half) * 256 + col * 8;
  const unsigned char* hrow = (const unsigned char*)hg + ((size_t)b * NPIX + n0 + col) * 512;

#pragma unroll 2
  for (int k0 = 0; k0 < NPIX; k0 += 32) {
    const unsigned wb = *(const unsigned*)(hrow + (k0 >> 3));
    const bf16x8 a0 = *(const bf16x8*)(pa);
    const bf16x8 a1 = *(const bf16x8*)(pa + 512);
    pa += 1024;
    const bf16x8 b0 = byte2bf((wb >> sh8) & 0xFFu);
    const bf16x8 b1 = byte2bf((wb >> (16 + sh8)) & 0xFFu);
    acc = __builtin_amdgcn_mfma_f32_32x32x16_bf16(a0, b0, acc, 0, 0, 0);
    acc = __builtin_amdgcn_mfma_f32_32x32x16_bf16(a1, b1, acc, 0, 0, 0);
  }

  const int n = n0 + col;
  const float dinv = dinvf[b * NPIX + n];
  short* dst = tbs2 + ((size_t)b << 20) + ((size_t)blockIdx.y * 512 + (n >> 3)) * 256 + (n & 7);
#pragma unroll
  for (int q = 0; q < 4; ++q)
#pragma unroll
    for (int rr = 0; rr < 4; ++rr) {
      const int c31 = rr + 8 * q + 4 * half;
      dst[c31 * 8] = f2b(acc[q * 4 + rr] * dinv);
    }
}

// ---------- hgemm_n: v[i][c] = (sum_j H[i][j] E^T[c][j]) * dinv[i] + xt[i][c], f32 out ----
// one wave per block; tile M=32 nodes x N=32 channels; K=4096
__global__ __launch_bounds__(64) void k_hgemm_n(const unsigned* __restrict__ hg,
                                                const short* __restrict__ tbs2,
                                                const float* __restrict__ dinvf,
                                                const float* __restrict__ resid,
                                                float* __restrict__ dst) {
  const int b = blockIdx.z;
  const int n0 = blockIdx.x * 32;   // channel tile (cb = blockIdx.x)
  const int m0 = blockIdx.y * 32;   // node tile
  const int l = threadIdx.x;
  const int col = l & 31, half = l >> 5;
  const int sh8 = half * 8;

  f32x16 acc;
#pragma unroll
  for (int r = 0; r < 16; ++r) acc[r] = 0.f;

  const short* pb = tbs2 + ((size_t)b << 20) + ((size_t)blockIdx.x * 512 + half) * 256 + col * 8;
  const unsigned char* hrow = (const unsigned char*)hg + ((size_t)b * NPIX + m0 + col) * 512;

#pragma unroll 2
  for (int k0 = 0; k0 < NPIX; k0 += 32) {
    const unsigned wb = *(const unsigned*)(hrow + (k0 >> 3));
    const bf16x8 b0 = *(const bf16x8*)(pb);
    const bf16x8 b1 = *(const bf16x8*)(pb + 512);
    pb += 1024;
    const bf16x8 a0 = byte2bf((wb >> sh8) & 0xFFu);
    const bf16x8 a1 = byte2bf((wb >> (16 + sh8)) & 0xFFu);
    acc = __builtin_amdgcn_mfma_f32_32x32x16_bf16(a0, b0, acc, 0, 0, 0);
    acc = __builtin_amdgcn_mfma_f32_32x32x16_bf16(a1, b1, acc, 0, 0, 0);
  }

  const int cc = n0 + col;
#pragma unroll
  for (int q = 0; q < 4; ++q) {
    const float4 dv = *(const float4*)(dinvf + b * NPIX + m0 + q * 8 + 4 * half);
    const float dvq[4] = {dv.x, dv.y, dv.z, dv.w};
#pragma unroll
    for (int rr = 0; rr < 4; ++rr) {
      const int r = m0 + rr + 8 * q + 4 * half;
      const size_t o = ((size_t)(b * NPIX + r)) * CH + cc;
      dst[o] = acc[q * 4 + rr] * dvq[rr] + resid[o];
    }
  }
}

// ---------- bf16 MFMA NT GEMM, f32 out + row bias (final 1x1 conv) ----------
__global__ __launch_bounds__(256) void k_mfma_nt(const short* __restrict__ A,
                                                 const short* __restrict__ B,
                                                 float* __restrict__ C,
                                                 const float* __restrict__ bias,
                                                 int N, int K,
                                                 int bStride, int cStride) {
  B += (size_t)blockIdx.z * bStride;
  C += (size_t)blockIdx.z * cStride;
  const int t = threadIdx.x, l = t & 63, wid = t >> 6;
  const int m0 = blockIdx.y * 128 + wid * 32, n0 = blockIdx.x * 64;
  const int col = l & 31, half = l >> 5;
  f32x16 acc[2];
#pragma unroll
  for (int nt = 0; nt < 2; ++nt)
#pragma unroll
    for (int r = 0; r < 16; ++r) acc[nt][r] = 0.f;
  const short* pa = A + (size_t)(m0 + col) * K + half * 8;
  const short* pb0 = B + (size_t)(n0 + col) * K + half * 8;
  const short* pb1 = pb0 + 32 * K;
  for (int k0 = 0; k0 < K; k0 += 16) {
    const bf16x8 a = *(const bf16x8*)(pa + k0);
    const bf16x8 b0 = *(const bf16x8*)(pb0 + k0);
    const bf16x8 b1 = *(const bf16x8*)(pb1 + k0);
    acc[0] = __builtin_amdgcn_mfma_f32_32x32x16_bf16(a, b0, acc[0], 0, 0, 0);
    acc[1] = __builtin_amdgcn_mfma_f32_32x32x16_bf16(a, b1, acc[1], 0, 0, 0);
  }
#pragma unroll
  for (int nt = 0; nt < 2; ++nt) {
#pragma unroll
    for (int q = 0; q < 4; ++q)
#pragma unroll
      for (int rr = 0; rr < 4; ++rr) {
        const int reg = q * 4 + rr;
        const int row = m0 + rr + 8 * q + 4 * half;
        const int cc = n0 + nt * 32 + col;
        C[(size_t)row * N + cc] = acc[nt][reg] + bias[row];
      }
  }
}

// ---------- fc GEMM: yT = fc_w @ xf^T + fc_b, SWIZZLED bf16 out ----------
// swizzle: [cb=c>>5][kb=node>>3][c&31][node&7]
__global__ __launch_bounds__(256) void k_mfma_fc(const short* __restrict__ A,
                                                 const short* __restrict__ B,
                                                 short* __restrict__ C,
                                                 const float* __restrict__ bias,
                                                 int K, int bStride, int cStride) {
  B += (size_t)blockIdx.z * bStride;
  C += (size_t)blockIdx.z * cStride;
  const int t = threadIdx.x, l = t & 63, wid = t >> 6;
  const int m0 = blockIdx.y * 128 + wid * 32, n0 = blockIdx.x * 64;
  const int col = l & 31, half = l >> 5;
  f32x16 acc[2];
#pragma unroll
  for (int nt = 0; nt < 2; ++nt)
#pragma unroll
    for (int r = 0; r < 16; ++r) acc[nt][r] = 0.f;
  const short* pa = A + (size_t)(m0 + col) * K + half * 8;
  const short* pb0 = B + (size_t)(n0 + col) * K + half * 8;
  const short* pb1 = pb0 + 32 * K;
  for (int k0 = 0; k0 < K; k0 += 16) {
    const bf16x8 a = *(const bf16x8*)(pa + k0);
    const bf16x8 b0 = *(const bf16x8*)(pb0 + k0);
    const bf16x8 b1 = *(const bf16x8*)(pb1 + k0);
    acc[0] = __builtin_amdgcn_mfma_f32_32x32x16_bf16(a, b0, acc[0], 0, 0, 0);
    acc[1] = __builtin_amdgcn_mfma_f32_32x32x16_bf16(a, b1, acc[1], 0, 0, 0);
  }
  const int cb = m0 >> 5;
#pragma unroll
  for (int nt = 0; nt < 2; ++nt) {
    const int node = n0 + nt * 32 + col;
    short* dst = C + ((size_t)cb * 512 + (node >> 3)) * 256 + (node & 7);
#pragma unroll
    for (int q = 0; q < 4; ++q)
#pragma unroll
      for (int rr = 0; rr < 4; ++rr) {
        const int c31 = rr + 8 * q + 4 * half;
        dst[c31 * 8] = f2b(acc[nt][q * 4 + rr] + bias[m0 + c31]);
      }
  }
}

// ---------- BN statistics ----------
__global__ void k_bnstat(const float* __restrict__ xn, float* __restrict__ part) {
  const int t = threadIdx.x, blk = blockIdx.x;  // 128 blocks x 64 rows
  float s = 0.f, ss = 0.f;
  const float* p = xn + (size_t)blk * 64 * CH;
  for (int r = 0; r < 64; ++r) {
    const float v = p[r * CH + t];
    s += v; ss += v * v;
  }
  part[blk * 512 + t] = s;
  part[blk * 512 + 256 + t] = ss;
}

__global__ void k_bnfin(const float* __restrict__ part, const float* __restrict__ gamma,
                        const float* __restrict__ beta, float* __restrict__ bnss) {
  const int t = threadIdx.x;  // 256
  float s = 0.f, ss = 0.f;
  for (int i = 0; i < 128; ++i) { s += part[i * 512 + t]; ss += part[i * 512 + 256 + t]; }
  const float mean = s * (1.f / 8192.f);
  const float var = ss * (1.f / 8192.f) - mean * mean;
  const float inv = rsqrtf(var + 1e-5f);
  const float sc = gamma[t] * inv;
  bnss[t] = sc;
  bnss[256 + t] = beta[t] - mean * sc;
}

// ---------- BN apply + SiLU (elementwise, pixel-major) -> bf16 xab[b][n][c] ----------
__global__ void k_bnapply2(const float* __restrict__ y, const float* __restrict__ bnss,
                           short* __restrict__ xab) {
  const int i = blockIdx.x * 256 + threadIdx.x;  // 524288 float4 groups
  const float4 v = reinterpret_cast<const float4*>(y)[i];
  const int c0 = (i & 63) * 4;
  const float4 sc = *(const float4*)(bnss + c0);
  const float4 sh = *(const float4*)(bnss + 256 + c0);
  const float u0 = v.x * sc.x + sh.x;
  const float u1 = v.y * sc.y + sh.y;
  const float u2 = v.z * sc.z + sh.z;
  const float u3 = v.w * sc.w + sh.w;
  short4 o;
  o.x = f2b(u0 / (1.f + expf(-u0)));
  o.y = f2b(u1 / (1.f + expf(-u1)));
  o.z = f2b(u2 / (1.f + expf(-u2)));
  o.w = f2b(u3 / (1.f + expf(-u3)));
  reinterpret_cast<short4*>(xab)[i] = o;
}

// ---------- weight converts ----------
__global__ void k_wcvt(const float* __restrict__ src, short* __restrict__ dst, int n) {
  const int i = blockIdx.x * 256 + threadIdx.x;
  if (i < n) dst[i] = f2b(src[i]);
}

// dw[oc][c][kh][kw] -> w3[tap][oc][c] bf16
__global__ void k_w3(const float* __restrict__ dw, short* __restrict__ w3) {
  const int i = blockIdx.x * 256 + threadIdx.x;  // 589824
  const int oc = i / 2304;
  const int rem = i % 2304;       // c*9 + tap
  const int c = rem / 9, tap = rem % 9;
  w3[((size_t)tap * 256 + oc) * 256 + c] = f2b(dw[i]);
}

// ---------- 3x3 stride-2 conv via direct MFMA ----------
__global__ __launch_bounds__(64) void k_conv3(const short* __restrict__ xab,
                                              const short* __restrict__ w3,
                                              const float* __restrict__ db,
                                              short* __restrict__ xdTb) {
  const int ocg = blockIdx.x;  // 0..3 (64 oc each)
  const int oh = blockIdx.y;   // 0..31
  const int b = blockIdx.z;
  const int l = threadIdx.x;
  const int col = l & 31, half = l >> 5;
  const short* xb = xab + (size_t)b * NPIX * CH;
  const bf16x8 zv = {0, 0, 0, 0, 0, 0, 0, 0};
  f32x16 acc[2];
#pragma unroll
  for (int nt = 0; nt < 2; ++nt)
#pragma unroll
    for (int r = 0; r < 16; ++r) acc[nt][r] = 0.f;

  for (int kh = 0; kh < 3; ++kh) {
    const int ih = 2 * oh + kh;
    if (ih >= 64) continue;
#pragma unroll
    for (int kw = 0; kw < 3; ++kw) {
      const int iw = 2 * col + kw;
      const bool ok = iw < 64;
      const short* pa = xb + (size_t)(ih * 64 + iw) * CH + half * 8;
      const short* pb = w3 + (size_t)((kh * 3 + kw) * 256 + ocg * 64 + col) * CH + half * 8;
#pragma unroll
      for (int ks = 0; ks < 16; ++ks) {
        const bf16x8 a = ok ? *(const bf16x8*)(pa + ks * 16) : zv;
        const bf16x8 b0 = *(const bf16x8*)(pb + ks * 16);
        const bf16x8 b1 = *(const bf16x8*)(pb + 32 * CH + ks * 16);
        acc[0] = __builtin_amdgcn_mfma_f32_32x32x16_bf16(a, b0, acc[0], 0, 0, 0);
        acc[1] = __builtin_amdgcn_mfma_f32_32x32x16_bf16(a, b1, acc[1], 0, 0, 0);
      }
    }
  }
#pragma unroll
  for (int nt = 0; nt < 2; ++nt) {
    const int oc = ocg * 64 + nt * 32 + col;
    const float bv = db[oc];
#pragma unroll
    for (int q = 0; q < 4; ++q)
#pragma unroll
      for (int rr = 0; rr < 4; ++rr) {
        const int reg = q * 4 + rr;
        const int ow = rr + 8 * q + 4 * half;
        xdTb[((size_t)b * 1024 + oh * 32 + ow) * CH + oc] = f2b(acc[nt][reg] + bv);
      }
  }
}

extern "C" void kernel_launch(void* const* d_in, const int* in_sizes, int n_in,
                              void* d_out, int out_size, void* d_ws, size_t ws_size,
                              hipStream_t stream) {
  const float* x     = (const float*)d_in[0];
  const float* fc_w  = (const float*)d_in[1];
  const float* fc_b  = (const float*)d_in[2];
  const float* gamma = (const float*)d_in[3];
  const float* beta  = (const float*)d_in[4];
  const float* dw    = (const float*)d_in[5];
  const float* db    = (const float*)d_in[6];
  const float* ow    = (const float*)d_in[7];
  const float* ob    = (const float*)d_in[8];

  float* ws   = (float*)d_ws;
  float* xt   = ws + OFF_XT;
  float* v    = ws + OFF_Y;
  float* sqv  = ws + OFF_SQ;
  float* part = ws + OFF_PART;
  float* bnss = ws + OFF_BNSS;
  float* dinvf= ws + OFF_DINV;
  unsigned* hg = (unsigned*)(ws + OFF_HG);
  __hip_bfloat16* xbh = (__hip_bfloat16*)(ws + OFF_XBH);
  short* xab  = (short*)(ws + OFF_XBH);   // aliases xbh (dead after fc+gram)
  short* tbs  = (short*)(ws + OFF_TBS);   // swizzled y^T
  short* tbs2 = (short*)(ws + OFF_TBS2);  // swizzled E^T
  short* xdTb = (short*)(ws + OFF_TBS);   // aliases tbs (dead after hgemm_t)
  short* w3b  = (short*)(ws + OFF_W3);
  short* wfcb = (short*)(ws + OFF_WFC);
  short* woutb= (short*)(ws + OFF_WOUT);
  float* out  = (float*)d_out;

  k_transpose<<<dim3(128, 8, 2), dim3(32, 8), 0, stream>>>(x, xt, xbh);
  k_sq<<<8192, 64, 0, stream>>>(xt, sqv);
  k_wcvt<<<256, 256, 0, stream>>>(fc_w, wfcb, 65536);
  k_wcvt<<<512, 256, 0, stream>>>(ow, woutb, 131072);
  k_w3<<<2304, 256, 0, stream>>>(dw, w3b);
  k_gram_mfma<<<dim3(32, 32, 2), 256, 0, stream>>>(xbh, sqv, hg);
  // yT (swizzled) = fc_w @ xf^T + fc_b : M=256, N=4096, K=256 per batch
  k_mfma_fc<<<dim3(64, 2, 2), 256, 0, stream>>>(wfcb, (const short*)xbh, tbs, fc_b,
                                                256, NPIX * CH, 1 << 20);
  k_dinv<<<8192, 64, 0, stream>>>(hg, dinvf);
  // E^T (swizzled bf16) = (y^T . H^T) * dinv[n]
  k_hgemm_t<<<dim3(128, 8, 2), 64, 0, stream>>>(tbs, hg, dinvf, tbs2);
  // v = (H . E) * dinv[i] + xf  (f32 row-major)
  k_hgemm_n<<<dim3(8, 128, 2), 64, 0, stream>>>(hg, tbs2, dinvf, xt, v);
  // BN + SiLU -> bf16 pixel-major
  k_bnstat<<<128, 256, 0, stream>>>(v, part);
  k_bnfin<<<1, 256, 0, stream>>>(part, gamma, beta, bnss);
  k_bnapply2<<<2048, 256, 0, stream>>>(v, bnss, xab);
  // 3x3 s2 conv (MFMA) -> bf16 [b][px][oc]
  k_conv3<<<dim3(4, 32, 2), 64, 0, stream>>>(xab, w3b, db, xdTb);
  // out = out_w @ xdT^T + out_b : per batch M=512, N=1024, K=256 (row bias)
  k_mfma_nt<<<dim3(16, 4, 2), 256, 0, stream>>>(woutb, xdTb, out, ob,
                                                1024, 256, 1024 * 256, 512 * 1024);
}

// Round 7
// 172.712 us; speedup vs baseline: 43.7731x; 1.2708x over previous
//
#include <hip/hip_runtime.h>
#include <hip/hip_bf16.h>
#include <math.h>

#define NPIX 4096
#define CH   256

// ---- ws float offsets ----
#define OFF_XT   0u          // [2][4096][256] f32 residual (lives until hgemm_n)
#define OFF_Y    2097152u    // [2][4096][256] f32 v (hgemm_n out -> BN)
#define OFF_XP   4194304u    // bf16 packed x [2][128R][16kb][2h][32c][8]; later conv partials f32
#define OFF_TBS  5242880u    // bf16 swizzled y^T; later xdtb pack
#define OFF_TBS2 6291456u    // bf16 swizzled E^T; later xpp (conv input pack)
#define OFF_HG   7340032u    // uint32 [2][4096][128] incidence bitmask
#define OFF_SQ   8388608u    // [8192] f32
#define OFF_PART 8396800u    // [128][512] f32 BN partials
#define OFF_BNSS 8462336u    // [512] f32
#define OFF_DINV 8462848u    // [8192] f32 1/deg
#define OFF_W3P  8471040u    // bf16 [9tap][8ocR][16kb][2h][32c][8]
#define OFF_WFCP 8765952u    // bf16 packed fc_w [8R][16kb][2h][32c][8]
#define OFF_WOUTP 8798720u   // bf16 packed out_w [16R][16kb][2h][32c][8]
// end: 8864256 floats = 35.5 MB

typedef __attribute__((ext_vector_type(8))) short bf16x8;
typedef __attribute__((ext_vector_type(16))) float f32x16;

static __device__ __forceinline__ short f2b(float f) {
  __hip_bfloat16 h = __float2bfloat16(f);
  return *reinterpret_cast<short*>(&h);
}

// expand 8 incidence bits (byte) -> bf16x8 of {0,1}
static __device__ __forceinline__ bf16x8 byte2bf(unsigned byte) {
  union { unsigned u[4]; bf16x8 h; } r;
  r.u[0] = ((byte * 0x8001u) & 0x10001u) * 0x3F80u;
  r.u[1] = (((byte >> 2) * 0x8001u) & 0x10001u) * 0x3F80u;
  r.u[2] = (((byte >> 4) * 0x8001u) & 0x10001u) * 0x3F80u;
  r.u[3] = (((byte >> 6) * 0x8001u) & 0x10001u) * 0x3F80u;
  return r.h;
}

// pack offset for element (row m, k c) of an MFMA operand matrix with K=256:
// [m>>5][c>>4][(c>>3)&1][m&31][c&7], block stride 512 shorts
static __device__ __forceinline__ size_t packoff(int m, int c) {
  return ((size_t)((m >> 5) * 16 + (c >> 4)) * 2 + ((c >> 3) & 1)) * 256 + (m & 31) * 8 + (c & 7);
}

// ---------- transpose x[b][c][n] -> xt[b][n][c] (f32) + packed bf16 xp ----------
__global__ void k_transpose(const float* __restrict__ x, float* __restrict__ xt,
                            short* __restrict__ xp) {
  __shared__ float tile[32][33];
  const int b = blockIdx.z;
  const int n0 = blockIdx.x * 32, c0 = blockIdx.y * 32;
  const int tx = threadIdx.x, ty = threadIdx.y;
  const float* xb = x + (size_t)b * CH * NPIX;
  float* xtb = xt + (size_t)b * NPIX * CH;
  short* xpb = xp + (size_t)b * NPIX * CH;
#pragma unroll
  for (int k = 0; k < 4; ++k)
    tile[ty + k * 8][tx] = xb[(c0 + ty + k * 8) * NPIX + n0 + tx];
  __syncthreads();
#pragma unroll
  for (int k = 0; k < 4; ++k) {
    const float v = tile[tx][ty + k * 8];
    const int n = n0 + ty + k * 8, c = c0 + tx;
    xtb[(size_t)n * CH + c] = v;
    xpb[packoff(n, c)] = f2b(v);
  }
}

// ---------- row squared norms (f32) ----------
__global__ void k_sq(const float* __restrict__ xt, float* __restrict__ sq) {
  const int row = blockIdx.x;  // 0..8191
  const int t = threadIdx.x;   // 64
  const float4 v = reinterpret_cast<const float4*>(xt + (size_t)row * CH)[t];
  float s = v.x * v.x + v.y * v.y + v.z * v.z + v.w * v.w;
#pragma unroll
  for (int off = 32; off; off >>= 1) s += __shfl_down(s, off);
  if (t == 0) sq[row] = s;
}

// ---------- Gram via bf16 MFMA on packed operands, fused threshold -> bitmask ----------
__global__ __launch_bounds__(256) void k_gram2(const short* __restrict__ xp,
                                               const float* __restrict__ sq,
                                               unsigned* __restrict__ hgbit) {
  const int b = blockIdx.z;
  const int i0 = blockIdx.y * 128, j0 = blockIdx.x * 128;
  const int t = threadIdx.x;
  const int lane = t & 63, wid = t >> 6;
  const int wm = wid >> 1, wn = wid & 1;
  const int c = lane & 31, h = lane >> 5;
  const short* xb = xp + (size_t)b * NPIX * CH;
  const int ibase = i0 + wm * 64;
  const int jbase = j0 + wn * 64;

  f32x16 acc[2][2];
#pragma unroll
  for (int m = 0; m < 2; ++m)
#pragma unroll
    for (int n = 0; n < 2; ++n)
#pragma unroll
      for (int r = 0; r < 16; ++r) acc[m][n][r] = 0.f;

  // group base: R*16*512 shorts; lane slice at l*8
  const short* pa = xb + (size_t)(ibase >> 5) * 8192 + lane * 8;
  const short* pb = xb + (size_t)(jbase >> 5) * 8192 + lane * 8;

#pragma unroll 4
  for (int kb = 0; kb < 16; ++kb) {
    const bf16x8 a0 = *(const bf16x8*)(pa + kb * 512);
    const bf16x8 a1 = *(const bf16x8*)(pa + 8192 + kb * 512);
    const bf16x8 b0 = *(const bf16x8*)(pb + kb * 512);
    const bf16x8 b1 = *(const bf16x8*)(pb + 8192 + kb * 512);
    acc[0][0] = __builtin_amdgcn_mfma_f32_32x32x16_bf16(a0, b0, acc[0][0], 0, 0, 0);
    acc[0][1] = __builtin_amdgcn_mfma_f32_32x32x16_bf16(a0, b1, acc[0][1], 0, 0, 0);
    acc[1][0] = __builtin_amdgcn_mfma_f32_32x32x16_bf16(a1, b0, acc[1][0], 0, 0, 0);
    acc[1][1] = __builtin_amdgcn_mfma_f32_32x32x16_bf16(a1, b1, acc[1][1], 0, 0, 0);
  }

  const int sqb = b * NPIX;
#pragma unroll
  for (int m = 0; m < 2; ++m) {
    float4 sqa[4];
#pragma unroll
    for (int q = 0; q < 4; ++q)
      sqa[q] = *(const float4*)(sq + sqb + ibase + m * 32 + q * 8 + 4 * h);
#pragma unroll
    for (int n = 0; n < 2; ++n) {
      const float sj = sq[sqb + jbase + n * 32 + c];
      const int wj = (jbase + n * 32) >> 5;
#pragma unroll
      for (int q = 0; q < 4; ++q) {
        const float sqq[4] = {sqa[q].x, sqa[q].y, sqa[q].z, sqa[q].w};
#pragma unroll
        for (int rr = 0; rr < 4; ++rr) {
          const int reg = q * 4 + rr;
          const float d2 = sqq[rr] + sj - 2.f * acc[m][n][reg];
          const unsigned long long bal = __ballot(d2 < 100.f);
          if ((lane & 31) == reg) {
            const int row = ibase + m * 32 + rr + 8 * q + 4 * h;
            const unsigned wd = h ? (unsigned)(bal >> 32) : (unsigned)bal;
            hgbit[(size_t)(sqb + row) * 128 + wj] = wd;
          }
        }
      }
    }
  }
}

// ---------- 1/deg per row ----------
__global__ void k_dinv(const unsigned* __restrict__ hg, float* __restrict__ dinvf) {
  const int row = blockIdx.x, l = threadIdx.x;  // 64 thr
  const unsigned w0 = hg[(size_t)row * 128 + l * 2];
  const unsigned w1 = hg[(size_t)row * 128 + l * 2 + 1];
  int n = __popc(w0) + __popc(w1);
#pragma unroll
  for (int off = 32; off; off >>= 1) n += __shfl_down(n, off);
  if (l == 0) dinvf[row] = 1.0f / (float)n;
}

// ---------- hgemm_t: E^T = (y^T . H^T) * dinv[n], swizzled bf16 out ----------
__global__ __launch_bounds__(64) void k_hgemm_t(const short* __restrict__ tbs,
                                                const unsigned* __restrict__ hg,
                                                const float* __restrict__ dinvf,
                                                short* __restrict__ tbs2) {
  const int b = blockIdx.z;
  const int n0 = blockIdx.x * 32;   // node tile
  const int l = threadIdx.x;
  const int col = l & 31, half = l >> 5;
  const int sh8 = half * 8;

  f32x16 acc;
#pragma unroll
  for (int r = 0; r < 16; ++r) acc[r] = 0.f;

  const short* pa = tbs + ((size_t)b << 20) + ((size_t)blockIdx.y * 512 + half) * 256 + col * 8;
  const unsigned char* hrow = (const unsigned char*)hg + ((size_t)b * NPIX + n0 + col) * 512;

#pragma unroll 2
  for (int k0 = 0; k0 < NPIX; k0 += 32) {
    const unsigned wb = *(const unsigned*)(hrow + (k0 >> 3));
    const bf16x8 a0 = *(const bf16x8*)(pa);
    const bf16x8 a1 = *(const bf16x8*)(pa + 512);
    pa += 1024;
    const bf16x8 b0 = byte2bf((wb >> sh8) & 0xFFu);
    const bf16x8 b1 = byte2bf((wb >> (16 + sh8)) & 0xFFu);
    acc = __builtin_amdgcn_mfma_f32_32x32x16_bf16(a0, b0, acc, 0, 0, 0);
    acc = __builtin_amdgcn_mfma_f32_32x32x16_bf16(a1, b1, acc, 0, 0, 0);
  }

  const int n = n0 + col;
  const float dinv = dinvf[b * NPIX + n];
  short* dst = tbs2 + ((size_t)b << 20) + ((size_t)blockIdx.y * 512 + (n >> 3)) * 256 + (n & 7);
#pragma unroll
  for (int q = 0; q < 4; ++q)
#pragma unroll
    for (int rr = 0; rr < 4; ++rr) {
      const int c31 = rr + 8 * q + 4 * half;
      dst[c31 * 8] = f2b(acc[q * 4 + rr] * dinv);
    }
}

// ---------- hgemm_n: v = (H . E) * dinv[i] + xt, f32 out ----------
__global__ __launch_bounds__(64) void k_hgemm_n(const unsigned* __restrict__ hg,
                                                const short* __restrict__ tbs2,
                                                const float* __restrict__ dinvf,
                                                const float* __restrict__ resid,
                                                float* __restrict__ dst) {
  const int b = blockIdx.z;
  const int n0 = blockIdx.x * 32;   // channel tile
  const int m0 = blockIdx.y * 32;   // node tile
  const int l = threadIdx.x;
  const int col = l & 31, half = l >> 5;
  const int sh8 = half * 8;

  f32x16 acc;
#pragma unroll
  for (int r = 0; r < 16; ++r) acc[r] = 0.f;

  const short* pb = tbs2 + ((size_t)b << 20) + ((size_t)blockIdx.x * 512 + half) * 256 + col * 8;
  const unsigned char* hrow = (const unsigned char*)hg + ((size_t)b * NPIX + m0 + col) * 512;

#pragma unroll 2
  for (int k0 = 0; k0 < NPIX; k0 += 32) {
    const unsigned wb = *(const unsigned*)(hrow + (k0 >> 3));
    const bf16x8 b0 = *(const bf16x8*)(pb);
    const bf16x8 b1 = *(const bf16x8*)(pb + 512);
    pb += 1024;
    const bf16x8 a0 = byte2bf((wb >> sh8) & 0xFFu);
    const bf16x8 a1 = byte2bf((wb >> (16 + sh8)) & 0xFFu);
    acc = __builtin_amdgcn_mfma_f32_32x32x16_bf16(a0, b0, acc, 0, 0, 0);
    acc = __builtin_amdgcn_mfma_f32_32x32x16_bf16(a1, b1, acc, 0, 0, 0);
  }

  const int cc = n0 + col;
#pragma unroll
  for (int q = 0; q < 4; ++q) {
    const float4 dv = *(const float4*)(dinvf + b * NPIX + m0 + q * 8 + 4 * half);
    const float dvq[4] = {dv.x, dv.y, dv.z, dv.w};
#pragma unroll
    for (int rr = 0; rr < 4; ++rr) {
      const int r = m0 + rr + 8 * q + 4 * half;
      const size_t o = ((size_t)(b * NPIX + r)) * CH + cc;
      dst[o] = acc[q * 4 + rr] * dvq[rr] + resid[o];
    }
  }
}

// ---------- fc GEMM on packed operands -> swizzled bf16 yT ----------
__global__ __launch_bounds__(256) void k_mfma_fc2(const short* __restrict__ wfcp,
                                                  const short* __restrict__ xp,
                                                  short* __restrict__ C,
                                                  const float* __restrict__ bias) {
  const int b = blockIdx.z;
  xp += (size_t)b * NPIX * CH;
  C += (size_t)b << 20;
  const int t = threadIdx.x, l = t & 63, wid = t >> 6;
  const int m0 = blockIdx.y * 128 + wid * 32, n0 = blockIdx.x * 64;
  const int col = l & 31, half = l >> 5;
  f32x16 acc[2];
#pragma unroll
  for (int nt = 0; nt < 2; ++nt)
#pragma unroll
    for (int r = 0; r < 16; ++r) acc[nt][r] = 0.f;
  const short* pa = wfcp + (size_t)(m0 >> 5) * 8192 + l * 8;
  const short* pb = xp + (size_t)(n0 >> 5) * 8192 + l * 8;
#pragma unroll 4
  for (int kb = 0; kb < 16; ++kb) {
    const bf16x8 a = *(const bf16x8*)(pa + kb * 512);
    const bf16x8 b0 = *(const bf16x8*)(pb + kb * 512);
    const bf16x8 b1 = *(const bf16x8*)(pb + 8192 + kb * 512);
    acc[0] = __builtin_amdgcn_mfma_f32_32x32x16_bf16(a, b0, acc[0], 0, 0, 0);
    acc[1] = __builtin_amdgcn_mfma_f32_32x32x16_bf16(a, b1, acc[1], 0, 0, 0);
  }
  const int cb = m0 >> 5;
#pragma unroll
  for (int nt = 0; nt < 2; ++nt) {
    const int node = n0 + nt * 32 + col;
    short* dst = C + ((size_t)cb * 512 + (node >> 3)) * 256 + (node & 7);
#pragma unroll
    for (int q = 0; q < 4; ++q)
#pragma unroll
      for (int rr = 0; rr < 4; ++rr) {
        const int c31 = rr + 8 * q + 4 * half;
        dst[c31 * 8] = f2b(acc[nt][q * 4 + rr] + bias[m0 + c31]);
      }
  }
}

// ---------- BN statistics ----------
__global__ void k_bnstat(const float* __restrict__ xn, float* __restrict__ part) {
  const int t = threadIdx.x, blk = blockIdx.x;  // 128 blocks x 64 rows
  float s = 0.f, ss = 0.f;
  const float* p = xn + (size_t)blk * 64 * CH;
  for (int r = 0; r < 64; ++r) {
    const float v = p[r * CH + t];
    s += v; ss += v * v;
  }
  part[blk * 512 + t] = s;
  part[blk * 512 + 256 + t] = ss;
}

__global__ void k_bnfin(const float* __restrict__ part, const float* __restrict__ gamma,
                        const float* __restrict__ beta, float* __restrict__ bnss) {
  const int t = threadIdx.x;  // 256
  float s = 0.f, ss = 0.f;
  for (int i = 0; i < 128; ++i) { s += part[i * 512 + t]; ss += part[i * 512 + 256 + t]; }
  const float mean = s * (1.f / 8192.f);
  const float var = ss * (1.f / 8192.f) - mean * mean;
  const float inv = rsqrtf(var + 1e-5f);
  const float sc = gamma[t] * inv;
  bnss[t] = sc;
  bnss[256 + t] = beta[t] - mean * sc;
}

// ---------- BN apply + SiLU -> conv input pack xpp[b][p][ih][kb][h][ow][8] ----------
__global__ void k_bnapply3(const float* __restrict__ y, const float* __restrict__ bnss,
                           short* __restrict__ xpp) {
  const int i = blockIdx.x * 256 + threadIdx.x;  // 524288 float4 groups
  const float4 v = reinterpret_cast<const float4*>(y)[i];
  const int c0 = (i & 63) * 4;
  const int n = (i >> 6) & 4095;
  const int b = i >> 18;
  const float4 sc = *(const float4*)(bnss + c0);
  const float4 sh = *(const float4*)(bnss + 256 + c0);
  const float u0 = v.x * sc.x + sh.x;
  const float u1 = v.y * sc.y + sh.y;
  const float u2 = v.z * sc.z + sh.z;
  const float u3 = v.w * sc.w + sh.w;
  short4 o;
  o.x = f2b(u0 / (1.f + expf(-u0)));
  o.y = f2b(u1 / (1.f + expf(-u1)));
  o.z = f2b(u2 / (1.f + expf(-u2)));
  o.w = f2b(u3 / (1.f + expf(-u3)));
  const int ih = n >> 6, iw = n & 63;
  const int p = iw & 1, ow = iw >> 1;
  const size_t off = ((size_t)(((b * 2 + p) * 64 + ih) * 16 + (c0 >> 4)) * 2 + ((c0 >> 3) & 1)) * 256
                   + ow * 8 + (c0 & 7);
  *(short4*)(xpp + off) = o;
}

// ---------- weight packers ----------
__global__ void k_wpack(const float* __restrict__ src, short* __restrict__ dst, int n) {
  const int i = blockIdx.x * 256 + threadIdx.x;
  if (i >= n) return;
  const int m = i >> 8, c = i & 255;
  dst[packoff(m, c)] = f2b(src[i]);
}

// dw[oc][ch][kh][kw] -> w3p[tap][ocR][kb][h][c][8]
__global__ void k_w3p(const float* __restrict__ dw, short* __restrict__ w3p) {
  const int i = blockIdx.x * 256 + threadIdx.x;  // 589824
  const int oc = i / 2304;
  const int rem = i % 2304;       // c*9 + tap
  const int c = rem / 9, tap = rem % 9;
  const size_t off = ((size_t)((tap * 8 + (oc >> 5)) * 16 + (c >> 4)) * 2 + ((c >> 3) & 1)) * 256
                   + (oc & 31) * 8 + (c & 7);
  w3p[off] = f2b(dw[i]);
}

// ---------- 3x3 stride-2 conv via packed MFMA, channel-split 2-way ----------
__global__ __launch_bounds__(64) void k_conv4(const short* __restrict__ xpp,
                                              const short* __restrict__ w3p,
                                              float* __restrict__ convp) {
  const int ocg = blockIdx.x;   // 0..7 (32 oc)
  const int oh = blockIdx.y;    // 0..31
  const int bz = blockIdx.z;    // b*2 + kh2
  const int b = bz >> 1, kh2 = bz & 1;
  const int l = threadIdx.x;
  const int col = l & 31;
  const bf16x8 zv = {0, 0, 0, 0, 0, 0, 0, 0};

  f32x16 acc;
#pragma unroll
  for (int r = 0; r < 16; ++r) acc[r] = 0.f;

  for (int kh = 0; kh < 3; ++kh) {
    const int ih = 2 * oh + kh;
    if (ih >= 64) continue;
#pragma unroll
    for (int kw = 0; kw < 3; ++kw) {
      const int p = kw & 1;
      const short* pa = xpp + ((size_t)((b * 2 + p) * 64 + ih) * 16 + kh2 * 8) * 512
                      + l * 8 + (kw == 2 ? 8 : 0);
      const short* pb = w3p + ((size_t)((kh * 3 + kw) * 8 + ocg) * 16 + kh2 * 8) * 512 + l * 8;
      const bool kill = (kw == 2) && (col == 31);
#pragma unroll
      for (int kb = 0; kb < 8; ++kb) {
        bf16x8 a = *(const bf16x8*)(pa + kb * 512);
        if (kill) a = zv;
        const bf16x8 bb = *(const bf16x8*)(pb + kb * 512);
        acc = __builtin_amdgcn_mfma_f32_32x32x16_bf16(a, bb, acc, 0, 0, 0);
      }
    }
  }
  const int half = l >> 5;
  const int oc = ocg * 32 + col;
#pragma unroll
  for (int q = 0; q < 4; ++q)
#pragma unroll
    for (int rr = 0; rr < 4; ++rr) {
      const int ow = rr + 8 * q + 4 * half;
      convp[((size_t)(kh2 * 2 + b) * 1024 + oh * 32 + ow) * 256 + oc] = acc[q * 4 + rr];
    }
}

// ---------- merge conv halves + bias -> packed bf16 xdtb ----------
__global__ void k_convmerge2(const float* __restrict__ convp, const float* __restrict__ db,
                             short* __restrict__ xdtb) {
  const int i = blockIdx.x * 256 + threadIdx.x;  // 131072 groups of 4
  const int b = i >> 16, px = (i >> 6) & 1023, oc0 = (i & 63) * 4;
  const float4 h0 = *(const float4*)(convp + ((size_t)b * 1024 + px) * 256 + oc0);
  const float4 h1 = *(const float4*)(convp + ((size_t)(2 + b) * 1024 + px) * 256 + oc0);
  const float4 bv = *(const float4*)(db + oc0);
  short4 o;
  o.x = f2b(h0.x + h1.x + bv.x);
  o.y = f2b(h0.y + h1.y + bv.y);
  o.z = f2b(h0.z + h1.z + bv.z);
  o.w = f2b(h0.w + h1.w + bv.w);
  const size_t off = ((size_t)((b * 32 + (px >> 5)) * 16 + (oc0 >> 4)) * 2 + ((oc0 >> 3) & 1)) * 256
                   + (px & 31) * 8 + (oc0 & 7);
  *(short4*)(xdtb + off) = o;
}

// ---------- final 1x1 GEMM on packed operands, f32 out + row bias ----------
__global__ __launch_bounds__(256) void k_mfma_nt2(const short* __restrict__ woutp,
                                                  const short* __restrict__ xdtb,
                                                  float* __restrict__ C,
                                                  const float* __restrict__ bias) {
  const int b = blockIdx.z;
  xdtb += (size_t)b * 1024 * CH;
  C += (size_t)b * 512 * 1024;
  const int t = threadIdx.x, l = t & 63, wid = t >> 6;
  const int m0 = blockIdx.y * 128 + wid * 32, n0 = blockIdx.x * 64;
  const int col = l & 31, half = l >> 5;
  f32x16 acc[2];
#pragma unroll
  for (int nt = 0; nt < 2; ++nt)
#pragma unroll
    for (int r = 0; r < 16; ++r) acc[nt][r] = 0.f;
  const short* pa = woutp + (size_t)(m0 >> 5) * 8192 + l * 8;
  const short* pb = xdtb + (size_t)(n0 >> 5) * 8192 + l * 8;
#pragma unroll 4
  for (int kb = 0; kb < 16; ++kb) {
    const bf16x8 a = *(const bf16x8*)(pa + kb * 512);
    const bf16x8 b0 = *(const bf16x8*)(pb + kb * 512);
    const bf16x8 b1 = *(const bf16x8*)(pb + 8192 + kb * 512);
    acc[0] = __builtin_amdgcn_mfma_f32_32x32x16_bf16(a, b0, acc[0], 0, 0, 0);
    acc[1] = __builtin_amdgcn_mfma_f32_32x32x16_bf16(a, b1, acc[1], 0, 0, 0);
  }
#pragma unroll
  for (int nt = 0; nt < 2; ++nt) {
#pragma unroll
    for (int q = 0; q < 4; ++q)
#pragma unroll
      for (int rr = 0; rr < 4; ++rr) {
        const int row = m0 + rr + 8 * q + 4 * half;
        const int cc = n0 + nt * 32 + col;
        C[(size_t)row * 1024 + cc] = acc[nt][q * 4 + rr] + bias[row];
      }
  }
}

extern "C" void kernel_launch(void* const* d_in, const int* in_sizes, int n_in,
                              void* d_out, int out_size, void* d_ws, size_t ws_size,
                              hipStream_t stream) {
  const float* x     = (const float*)d_in[0];
  const float* fc_w  = (const float*)d_in[1];
  const float* fc_b  = (const float*)d_in[2];
  const float* gamma = (const float*)d_in[3];
  const float* beta  = (const float*)d_in[4];
  const float* dw    = (const float*)d_in[5];
  const float* db    = (const float*)d_in[6];
  const float* ow    = (const float*)d_in[7];
  const float* ob    = (const float*)d_in[8];

  float* ws   = (float*)d_ws;
  float* xt   = ws + OFF_XT;
  float* v    = ws + OFF_Y;
  float* sqv  = ws + OFF_SQ;
  float* part = ws + OFF_PART;
  float* bnss = ws + OFF_BNSS;
  float* dinvf= ws + OFF_DINV;
  unsigned* hg = (unsigned*)(ws + OFF_HG);
  short* xp   = (short*)(ws + OFF_XP);
  float* convp= ws + OFF_XP;              // aliases xp (dead after gram+fc)
  short* tbs  = (short*)(ws + OFF_TBS);
  short* xdtb = (short*)(ws + OFF_TBS);   // aliases tbs (dead after hgemm_t)
  short* tbs2 = (short*)(ws + OFF_TBS2);
  short* xpp  = (short*)(ws + OFF_TBS2);  // aliases tbs2 (dead after hgemm_n)
  short* w3p  = (short*)(ws + OFF_W3P);
  short* wfcp = (short*)(ws + OFF_WFCP);
  short* woutp= (short*)(ws + OFF_WOUTP);
  float* out  = (float*)d_out;

  k_transpose<<<dim3(128, 8, 2), dim3(32, 8), 0, stream>>>(x, xt, xp);
  k_sq<<<8192, 64, 0, stream>>>(xt, sqv);
  k_wpack<<<256, 256, 0, stream>>>(fc_w, wfcp, 65536);
  k_wpack<<<512, 256, 0, stream>>>(ow, woutp, 131072);
  k_w3p<<<2304, 256, 0, stream>>>(dw, w3p);
  k_gram2<<<dim3(32, 32, 2), 256, 0, stream>>>(xp, sqv, hg);
  // yT (swizzled bf16) = fc_w @ xf^T + fc_b
  k_mfma_fc2<<<dim3(64, 2, 2), 256, 0, stream>>>(wfcp, xp, tbs, fc_b);
  k_dinv<<<8192, 64, 0, stream>>>(hg, dinvf);
  // E^T (swizzled bf16) = (y^T . H^T) * dinv[n]
  k_hgemm_t<<<dim3(128, 8, 2), 64, 0, stream>>>(tbs, hg, dinvf, tbs2);
  // v = (H . E) * dinv[i] + xf  (f32 row-major)
  k_hgemm_n<<<dim3(8, 128, 2), 64, 0, stream>>>(hg, tbs2, dinvf, xt, v);
  // BN + SiLU -> conv input pack
  k_bnstat<<<128, 256, 0, stream>>>(v, part);
  k_bnfin<<<1, 256, 0, stream>>>(part, gamma, beta, bnss);
  k_bnapply3<<<2048, 256, 0, stream>>>(v, bnss, xpp);
  // 3x3 s2 conv (packed MFMA, K split 2-way) -> f32 partials -> packed bf16
  k_conv4<<<dim3(8, 32, 4), 64, 0, stream>>>(xpp, w3p, convp);
  k_convmerge2<<<512, 256, 0, stream>>>(convp, db, xdtb);
  // out = out_w @ xdT^T + out_b
  k_mfma_nt2<<<dim3(16, 4, 2), 256, 0, stream>>>(woutp, xdtb, out, ob);
}

// Round 8
// 172.002 us; speedup vs baseline: 43.9539x; 1.0041x over previous
//
#include <hip/hip_runtime.h>
#include <hip/hip_bf16.h>
#include <math.h>

#define NPIX 4096
#define CH   256

// ---- ws float offsets ----
#define OFF_XP    0u         // bf16 packed x [2][128R][16kb][2h][32][8]; later convp f32 [4][1024][256]
#define OFF_XR    1048576u   // bf16 row-major x [2][4096][256] (residual)
#define OFF_VB    2097152u   // bf16 v [2][4096][256] (BN input)
#define OFF_TBS   3145728u   // bf16 swizzled y^T; later xdtb pack
#define OFF_TBS2  4194304u   // bf16 swizzled E^T; later xpp conv input pack
#define OFF_HG    5242880u   // uint32 [2][4096][128] incidence bitmask
#define OFF_SQ    6291456u   // [8192] f32
#define OFF_PART  6299648u   // [128][512] f32 BN partials
#define OFF_BNSS  6365184u   // [512] f32
#define OFF_DINV  6365696u   // [8192] f32 1/deg
#define OFF_W3P   6373888u   // bf16 [9tap][8ocR][16kb][2h][32][8]
#define OFF_WFCP  6668800u   // bf16 packed fc_w
#define OFF_WOUTP 6701568u   // bf16 packed out_w
// end: 6767104 floats = 27.1 MB

typedef __attribute__((ext_vector_type(8))) short bf16x8;
typedef __attribute__((ext_vector_type(16))) float f32x16;

static __device__ __forceinline__ short f2b(float f) {
  __hip_bfloat16 h = __float2bfloat16(f);
  return *reinterpret_cast<short*>(&h);
}
static __device__ __forceinline__ float b2f(short s) {
  union { unsigned u; float f; } r;
  r.u = ((unsigned)(unsigned short)s) << 16;
  return r.f;
}

// expand 8 incidence bits (byte) -> bf16x8 of {0,1}
static __device__ __forceinline__ bf16x8 byte2bf(unsigned byte) {
  union { unsigned u[4]; bf16x8 h; } r;
  r.u[0] = ((byte * 0x8001u) & 0x10001u) * 0x3F80u;
  r.u[1] = (((byte >> 2) * 0x8001u) & 0x10001u) * 0x3F80u;
  r.u[2] = (((byte >> 4) * 0x8001u) & 0x10001u) * 0x3F80u;
  r.u[3] = (((byte >> 6) * 0x8001u) & 0x10001u) * 0x3F80u;
  return r.h;
}

// pack offset for element (row m, k c), K=256: [m>>5][c>>4][(c>>3)&1][m&31][c&7]
static __device__ __forceinline__ size_t packoff(int m, int c) {
  return ((size_t)((m >> 5) * 16 + (c >> 4)) * 2 + ((c >> 3) & 1)) * 256 + (m & 31) * 8 + (c & 7);
}

// ---------- transpose x[b][c][n] -> packed bf16 xp + row-major bf16 xr ----------
__global__ void k_transpose(const float* __restrict__ x, short* __restrict__ xp,
                            short* __restrict__ xr) {
  __shared__ float tile[32][33];
  const int b = blockIdx.z;
  const int n0 = blockIdx.x * 32, c0 = blockIdx.y * 32;
  const int tx = threadIdx.x, ty = threadIdx.y;
  const float* xb = x + (size_t)b * CH * NPIX;
  short* xpb = xp + (size_t)b * NPIX * CH;
  short* xrb = xr + (size_t)b * NPIX * CH;
#pragma unroll
  for (int k = 0; k < 4; ++k)
    tile[ty + k * 8][tx] = xb[(c0 + ty + k * 8) * NPIX + n0 + tx];
  __syncthreads();
#pragma unroll
  for (int k = 0; k < 4; ++k) {
    const int n = n0 + ty + k * 8, c = c0 + tx;
    const short s = f2b(tile[tx][ty + k * 8]);
    xrb[(size_t)n * CH + c] = s;
    xpb[packoff(n, c)] = s;
  }
}

// ---------- row squared norms directly from x (f32 exact) ----------
__global__ void k_sqx(const float* __restrict__ x, float* __restrict__ sq) {
  const int b = blockIdx.y, n0 = blockIdx.x * 64;
  const int t = threadIdx.x;             // 256
  const int nl = t & 63, cg = t >> 6;    // 4 channel groups of 64
  const float* xb = x + (size_t)b * CH * NPIX;
  float s = 0.f;
#pragma unroll 4
  for (int c = cg * 64; c < cg * 64 + 64; ++c) {
    const float v = xb[(size_t)c * NPIX + n0 + nl];
    s += v * v;
  }
  __shared__ float red[256];
  red[t] = s;
  __syncthreads();
  if (t < 64) sq[b * NPIX + n0 + t] = red[t] + red[64 + t] + red[128 + t] + red[192 + t];
}

// ---------- fused weight packers ----------
__global__ void k_packall(const float* __restrict__ fc_w, const float* __restrict__ ow,
                          const float* __restrict__ dw, short* __restrict__ wfcp,
                          short* __restrict__ woutp, short* __restrict__ w3p) {
  const int i = blockIdx.x * 256 + threadIdx.x;  // 786432
  if (i < 65536) {
    wfcp[packoff(i >> 8, i & 255)] = f2b(fc_w[i]);
  } else if (i < 196608) {
    const int j = i - 65536;
    woutp[packoff(j >> 8, j & 255)] = f2b(ow[j]);
  } else {
    const int j = i - 196608;        // dw[oc][c][kh][kw]
    const int oc = j / 2304;
    const int rem = j % 2304;
    const int c = rem / 9, tap = rem % 9;
    const size_t off = ((size_t)((tap * 8 + (oc >> 5)) * 16 + (c >> 4)) * 2 + ((c >> 3) & 1)) * 256
                     + (oc & 31) * 8 + (c & 7);
    w3p[off] = f2b(dw[j]);
  }
}

// ---------- Gram via bf16 MFMA on packed operands, fused threshold -> bitmask ----------
__global__ __launch_bounds__(256) void k_gram2(const short* __restrict__ xp,
                                               const float* __restrict__ sq,
                                               unsigned* __restrict__ hgbit) {
  const int b = blockIdx.z;
  const int i0 = blockIdx.y * 128, j0 = blockIdx.x * 128;
  const int t = threadIdx.x;
  const int lane = t & 63, wid = t >> 6;
  const int wm = wid >> 1, wn = wid & 1;
  const int c = lane & 31, h = lane >> 5;
  const short* xb = xp + (size_t)b * NPIX * CH;
  const int ibase = i0 + wm * 64;
  const int jbase = j0 + wn * 64;

  f32x16 acc[2][2];
#pragma unroll
  for (int m = 0; m < 2; ++m)
#pragma unroll
    for (int n = 0; n < 2; ++n)
#pragma unroll
      for (int r = 0; r < 16; ++r) acc[m][n][r] = 0.f;

  const short* pa = xb + (size_t)(ibase >> 5) * 8192 + lane * 8;
  const short* pb = xb + (size_t)(jbase >> 5) * 8192 + lane * 8;

#pragma unroll 4
  for (int kb = 0; kb < 16; ++kb) {
    const bf16x8 a0 = *(const bf16x8*)(pa + kb * 512);
    const bf16x8 a1 = *(const bf16x8*)(pa + 8192 + kb * 512);
    const bf16x8 b0 = *(const bf16x8*)(pb + kb * 512);
    const bf16x8 b1 = *(const bf16x8*)(pb + 8192 + kb * 512);
    acc[0][0] = __builtin_amdgcn_mfma_f32_32x32x16_bf16(a0, b0, acc[0][0], 0, 0, 0);
    acc[0][1] = __builtin_amdgcn_mfma_f32_32x32x16_bf16(a0, b1, acc[0][1], 0, 0, 0);
    acc[1][0] = __builtin_amdgcn_mfma_f32_32x32x16_bf16(a1, b0, acc[1][0], 0, 0, 0);
    acc[1][1] = __builtin_amdgcn_mfma_f32_32x32x16_bf16(a1, b1, acc[1][1], 0, 0, 0);
  }

  const int sqb = b * NPIX;
#pragma unroll
  for (int m = 0; m < 2; ++m) {
    float4 sqa[4];
#pragma unroll
    for (int q = 0; q < 4; ++q)
      sqa[q] = *(const float4*)(sq + sqb + ibase + m * 32 + q * 8 + 4 * h);
#pragma unroll
    for (int n = 0; n < 2; ++n) {
      const float sj = sq[sqb + jbase + n * 32 + c];
      const int wj = (jbase + n * 32) >> 5;
#pragma unroll
      for (int q = 0; q < 4; ++q) {
        const float sqq[4] = {sqa[q].x, sqa[q].y, sqa[q].z, sqa[q].w};
#pragma unroll
        for (int rr = 0; rr < 4; ++rr) {
          const int reg = q * 4 + rr;
          const float d2 = sqq[rr] + sj - 2.f * acc[m][n][reg];
          const unsigned long long bal = __ballot(d2 < 100.f);
          if ((lane & 31) == reg) {
            const int row = ibase + m * 32 + rr + 8 * q + 4 * h;
            const unsigned wd = h ? (unsigned)(bal >> 32) : (unsigned)bal;
            hgbit[(size_t)(sqb + row) * 128 + wj] = wd;
          }
        }
      }
    }
  }
}

// ---------- 1/deg per row ----------
__global__ void k_dinv(const unsigned* __restrict__ hg, float* __restrict__ dinvf) {
  const int row = blockIdx.x, l = threadIdx.x;  // 64 thr
  const unsigned w0 = hg[(size_t)row * 128 + l * 2];
  const unsigned w1 = hg[(size_t)row * 128 + l * 2 + 1];
  int n = __popc(w0) + __popc(w1);
#pragma unroll
  for (int off = 32; off; off >>= 1) n += __shfl_down(n, off);
  if (l == 0) dinvf[row] = 1.0f / (float)n;
}

// ---------- fc GEMM on packed operands -> swizzled bf16 yT ----------
__global__ __launch_bounds__(256) void k_mfma_fc2(const short* __restrict__ wfcp,
                                                  const short* __restrict__ xp,
                                                  short* __restrict__ C,
                                                  const float* __restrict__ bias) {
  const int b = blockIdx.z;
  xp += (size_t)b * NPIX * CH;
  C += (size_t)b << 20;
  const int t = threadIdx.x, l = t & 63, wid = t >> 6;
  const int m0 = blockIdx.y * 128 + wid * 32, n0 = blockIdx.x * 64;
  const int col = l & 31, half = l >> 5;
  f32x16 acc[2];
#pragma unroll
  for (int nt = 0; nt < 2; ++nt)
#pragma unroll
    for (int r = 0; r < 16; ++r) acc[nt][r] = 0.f;
  const short* pa = wfcp + (size_t)(m0 >> 5) * 8192 + l * 8;
  const short* pb = xp + (size_t)(n0 >> 5) * 8192 + l * 8;
#pragma unroll 4
  for (int kb = 0; kb < 16; ++kb) {
    const bf16x8 a = *(const bf16x8*)(pa + kb * 512);
    const bf16x8 b0 = *(const bf16x8*)(pb + kb * 512);
    const bf16x8 b1 = *(const bf16x8*)(pb + 8192 + kb * 512);
    acc[0] = __builtin_amdgcn_mfma_f32_32x32x16_bf16(a, b0, acc[0], 0, 0, 0);
    acc[1] = __builtin_amdgcn_mfma_f32_32x32x16_bf16(a, b1, acc[1], 0, 0, 0);
  }
  const int cb = m0 >> 5;
#pragma unroll
  for (int nt = 0; nt < 2; ++nt) {
    const int node = n0 + nt * 32 + col;
    short* dst = C + ((size_t)cb * 512 + (node >> 3)) * 256 + (node & 7);
#pragma unroll
    for (int q = 0; q < 4; ++q)
#pragma unroll
      for (int rr = 0; rr < 4; ++rr) {
        const int c31 = rr + 8 * q + 4 * half;
        dst[c31 * 8] = f2b(acc[nt][q * 4 + rr] + bias[m0 + c31]);
      }
  }
}

// ---------- hgemm_t2: E^T = (y^T . H^T) * dinv[n], 2 channel tiles/wave ----------
__global__ __launch_bounds__(64) void k_hgemm_t2(const short* __restrict__ tbs,
                                                 const unsigned* __restrict__ hg,
                                                 const float* __restrict__ dinvf,
                                                 short* __restrict__ tbs2) {
  const int b = blockIdx.z;
  const int n0 = blockIdx.x * 32;   // node tile (128)
  const int cbp = blockIdx.y;       // cb pair (4)
  const int l = threadIdx.x;
  const int col = l & 31, half = l >> 5;
  const int sh8 = half * 8;

  f32x16 acc0, acc1;
#pragma unroll
  for (int r = 0; r < 16; ++r) { acc0[r] = 0.f; acc1[r] = 0.f; }

  const short* pa0 = tbs + ((size_t)b << 20) + ((size_t)(cbp * 2) * 512 + half) * 256 + col * 8;
  const short* pa1 = pa0 + 131072;
  const unsigned char* hrow = (const unsigned char*)hg + ((size_t)b * NPIX + n0 + col) * 512;

#pragma unroll 2
  for (int k0 = 0; k0 < NPIX; k0 += 32) {
    const unsigned wb = *(const unsigned*)(hrow + (k0 >> 3));
    const bf16x8 a00 = *(const bf16x8*)(pa0);
    const bf16x8 a01 = *(const bf16x8*)(pa0 + 512);
    const bf16x8 a10 = *(const bf16x8*)(pa1);
    const bf16x8 a11 = *(const bf16x8*)(pa1 + 512);
    pa0 += 1024; pa1 += 1024;
    const bf16x8 b0 = byte2bf((wb >> sh8) & 0xFFu);
    const bf16x8 b1 = byte2bf((wb >> (16 + sh8)) & 0xFFu);
    acc0 = __builtin_amdgcn_mfma_f32_32x32x16_bf16(a00, b0, acc0, 0, 0, 0);
    acc0 = __builtin_amdgcn_mfma_f32_32x32x16_bf16(a01, b1, acc0, 0, 0, 0);
    acc1 = __builtin_amdgcn_mfma_f32_32x32x16_bf16(a10, b0, acc1, 0, 0, 0);
    acc1 = __builtin_amdgcn_mfma_f32_32x32x16_bf16(a11, b1, acc1, 0, 0, 0);
  }

  const int n = n0 + col;
  const float dinv = dinvf[b * NPIX + n];
  short* dst0 = tbs2 + ((size_t)b << 20) + ((size_t)(cbp * 2) * 512 + (n >> 3)) * 256 + (n & 7);
  short* dst1 = dst0 + 131072;
#pragma unroll
  for (int q = 0; q < 4; ++q)
#pragma unroll
    for (int rr = 0; rr < 4; ++rr) {
      const int c31 = rr + 8 * q + 4 * half;
      dst0[c31 * 8] = f2b(acc0[q * 4 + rr] * dinv);
      dst1[c31 * 8] = f2b(acc1[q * 4 + rr] * dinv);
    }
}

// ---------- hgemm_n2: v = (H . E) * dinv[i] + xr, bf16 out, 2 channel tiles/wave ----------
__global__ __launch_bounds__(64) void k_hgemm_n2(const unsigned* __restrict__ hg,
                                                 const short* __restrict__ tbs2,
                                                 const float* __restrict__ dinvf,
                                                 const short* __restrict__ xr,
                                                 short* __restrict__ vb) {
  const int b = blockIdx.z;
  const int cbp = blockIdx.x;       // cb pair (4)
  const int m0 = blockIdx.y * 32;   // node tile (128)
  const int l = threadIdx.x;
  const int col = l & 31, half = l >> 5;
  const int sh8 = half * 8;

  f32x16 acc0, acc1;
#pragma unroll
  for (int r = 0; r < 16; ++r) { acc0[r] = 0.f; acc1[r] = 0.f; }

  const short* pb0 = tbs2 + ((size_t)b << 20) + ((size_t)(cbp * 2) * 512 + half) * 256 + col * 8;
  const short* pb1 = pb0 + 131072;
  const unsigned char* hrow = (const unsigned char*)hg + ((size_t)b * NPIX + m0 + col) * 512;

#pragma unroll 2
  for (int k0 = 0; k0 < NPIX; k0 += 32) {
    const unsigned wb = *(const unsigned*)(hrow + (k0 >> 3));
    const bf16x8 b00 = *(const bf16x8*)(pb0);
    const bf16x8 b01 = *(const bf16x8*)(pb0 + 512);
    const bf16x8 b10 = *(const bf16x8*)(pb1);
    const bf16x8 b11 = *(const bf16x8*)(pb1 + 512);
    pb0 += 1024; pb1 += 1024;
    const bf16x8 a0 = byte2bf((wb >> sh8) & 0xFFu);
    const bf16x8 a1 = byte2bf((wb >> (16 + sh8)) & 0xFFu);
    acc0 = __builtin_amdgcn_mfma_f32_32x32x16_bf16(a0, b00, acc0, 0, 0, 0);
    acc0 = __builtin_amdgcn_mfma_f32_32x32x16_bf16(a1, b01, acc0, 0, 0, 0);
    acc1 = __builtin_amdgcn_mfma_f32_32x32x16_bf16(a0, b10, acc1, 0, 0, 0);
    acc1 = __builtin_amdgcn_mfma_f32_32x32x16_bf16(a1, b11, acc1, 0, 0, 0);
  }

  const int cc = cbp * 64 + col;
#pragma unroll
  for (int q = 0; q < 4; ++q) {
    const float4 dv = *(const float4*)(dinvf + b * NPIX + m0 + q * 8 + 4 * half);
    const float dvq[4] = {dv.x, dv.y, dv.z, dv.w};
#pragma unroll
    for (int rr = 0; rr < 4; ++rr) {
      const int r = m0 + rr + 8 * q + 4 * half;
      const size_t o = ((size_t)(b * NPIX + r)) * CH + cc;
      vb[o] = f2b(acc0[q * 4 + rr] * dvq[rr] + b2f(xr[o]));
      vb[o + 32] = f2b(acc1[q * 4 + rr] * dvq[rr] + b2f(xr[o + 32]));
    }
  }
}

// ---------- BN statistics (bf16 input) ----------
__global__ void k_bnstat(const short* __restrict__ vb, float* __restrict__ part) {
  const int t = threadIdx.x, blk = blockIdx.x;  // 128 blocks x 64 rows
  float s = 0.f, ss = 0.f;
  const short* p = vb + (size_t)blk * 64 * CH;
  for (int r = 0; r < 64; ++r) {
    const float v = b2f(p[r * CH + t]);
    s += v; ss += v * v;
  }
  part[blk * 512 + t] = s;
  part[blk * 512 + 256 + t] = ss;
}

__global__ void k_bnfin(const float* __restrict__ part, const float* __restrict__ gamma,
                        const float* __restrict__ beta, float* __restrict__ bnss) {
  const int t = threadIdx.x;  // 256
  float s = 0.f, ss = 0.f;
  for (int i = 0; i < 128; ++i) { s += part[i * 512 + t]; ss += part[i * 512 + 256 + t]; }
  const float mean = s * (1.f / 8192.f);
  const float var = ss * (1.f / 8192.f) - mean * mean;
  const float inv = rsqrtf(var + 1e-5f);
  const float sc = gamma[t] * inv;
  bnss[t] = sc;
  bnss[256 + t] = beta[t] - mean * sc;
}

// ---------- BN apply + SiLU (bf16 in) -> conv input pack ----------
__global__ void k_bnapply3(const short* __restrict__ vb, const float* __restrict__ bnss,
                           short* __restrict__ xpp) {
  const int i = blockIdx.x * 256 + threadIdx.x;  // 524288 short4 groups
  const short4 sv = reinterpret_cast<const short4*>(vb)[i];
  const int c0 = (i & 63) * 4;
  const int n = (i >> 6) & 4095;
  const int b = i >> 18;
  const float4 sc = *(const float4*)(bnss + c0);
  const float4 sh = *(const float4*)(bnss + 256 + c0);
  const float u0 = b2f(sv.x) * sc.x + sh.x;
  const float u1 = b2f(sv.y) * sc.y + sh.y;
  const float u2 = b2f(sv.z) * sc.z + sh.z;
  const float u3 = b2f(sv.w) * sc.w + sh.w;
  short4 o;
  o.x = f2b(u0 / (1.f + expf(-u0)));
  o.y = f2b(u1 / (1.f + expf(-u1)));
  o.z = f2b(u2 / (1.f + expf(-u2)));
  o.w = f2b(u3 / (1.f + expf(-u3)));
  const int ih = n >> 6, iw = n & 63;
  const int p = iw & 1, ow = iw >> 1;
  const size_t off = ((size_t)(((b * 2 + p) * 64 + ih) * 16 + (c0 >> 4)) * 2 + ((c0 >> 3) & 1)) * 256
                   + ow * 8 + (c0 & 7);
  *(short4*)(xpp + off) = o;
}

// ---------- 3x3 stride-2 conv via packed MFMA, channel-split 2-way ----------
__global__ __launch_bounds__(64) void k_conv4(const short* __restrict__ xpp,
                                              const short* __restrict__ w3p,
                                              float* __restrict__ convp) {
  const int ocg = blockIdx.x;   // 0..7 (32 oc)
  const int oh = blockIdx.y;    // 0..31
  const int bz = blockIdx.z;    // b*2 + kh2
  const int b = bz >> 1, kh2 = bz & 1;
  const int l = threadIdx.x;
  const int col = l & 31;
  const bf16x8 zv = {0, 0, 0, 0, 0, 0, 0, 0};

  f32x16 acc;
#pragma unroll
  for (int r = 0; r < 16; ++r) acc[r] = 0.f;

  for (int kh = 0; kh < 3; ++kh) {
    const int ih = 2 * oh + kh;
    if (ih >= 64) continue;
#pragma unroll
    for (int kw = 0; kw < 3; ++kw) {
      const int p = kw & 1;
      const short* pa = xpp + ((size_t)((b * 2 + p) * 64 + ih) * 16 + kh2 * 8) * 512
                      + l * 8 + (kw == 2 ? 8 : 0);
      const short* pb = w3p + ((size_t)((kh * 3 + kw) * 8 + ocg) * 16 + kh2 * 8) * 512 + l * 8;
      const bool kill = (kw == 2) && (col == 31);
#pragma unroll
      for (int kb = 0; kb < 8; ++kb) {
        bf16x8 a = *(const bf16x8*)(pa + kb * 512);
        if (kill) a = zv;
        const bf16x8 bb = *(const bf16x8*)(pb + kb * 512);
        acc = __builtin_amdgcn_mfma_f32_32x32x16_bf16(a, bb, acc, 0, 0, 0);
      }
    }
  }
  const int half = l >> 5;
  const int oc = ocg * 32 + col;
#pragma unroll
  for (int q = 0; q < 4; ++q)
#pragma unroll
    for (int rr = 0; rr < 4; ++rr) {
      const int ow = rr + 8 * q + 4 * half;
      convp[((size_t)(kh2 * 2 + b) * 1024 + oh * 32 + ow) * 256 + oc] = acc[q * 4 + rr];
    }
}

// ---------- merge conv halves + bias -> packed bf16 xdtb ----------
__global__ void k_convmerge2(const float* __restrict__ convp, const float* __restrict__ db,
                             short* __restrict__ xdtb) {
  const int i = blockIdx.x * 256 + threadIdx.x;  // 131072 groups of 4
  const int b = i >> 16, px = (i >> 6) & 1023, oc0 = (i & 63) * 4;
  const float4 h0 = *(const float4*)(convp + ((size_t)b * 1024 + px) * 256 + oc0);
  const float4 h1 = *(const float4*)(convp + ((size_t)(2 + b) * 1024 + px) * 256 + oc0);
  const float4 bv = *(const float4*)(db + oc0);
  short4 o;
  o.x = f2b(h0.x + h1.x + bv.x);
  o.y = f2b(h0.y + h1.y + bv.y);
  o.z = f2b(h0.z + h1.z + bv.z);
  o.w = f2b(h0.w + h1.w + bv.w);
  const size_t off = ((size_t)((b * 32 + (px >> 5)) * 16 + (oc0 >> 4)) * 2 + ((oc0 >> 3) & 1)) * 256
                   + (px & 31) * 8 + (oc0 & 7);
  *(short4*)(xdtb + off) = o;
}

// ---------- final 1x1 GEMM on packed operands, f32 out + row bias ----------
__global__ __launch_bounds__(256) void k_mfma_nt2(const short* __restrict__ woutp,
                                                  const short* __restrict__ xdtb,
                                                  float* __restrict__ C,
                                                  const float* __restrict__ bias) {
  const int b = blockIdx.z;
  xdtb += (size_t)b * 1024 * CH;
  C += (size_t)b * 512 * 1024;
  const int t = threadIdx.x, l = t & 63, wid = t >> 6;
  const int m0 = blockIdx.y * 128 + wid * 32, n0 = blockIdx.x * 64;
  const int col = l & 31, half = l >> 5;
  f32x16 acc[2];
#pragma unroll
  for (int nt = 0; nt < 2; ++nt)
#pragma unroll
    for (int r = 0; r < 16; ++r) acc[nt][r] = 0.f;
  const short* pa = woutp + (size_t)(m0 >> 5) * 8192 + l * 8;
  const short* pb = xdtb + (size_t)(n0 >> 5) * 8192 + l * 8;
#pragma unroll 4
  for (int kb = 0; kb < 16; ++kb) {
    const bf16x8 a = *(const bf16x8*)(pa + kb * 512);
    const bf16x8 b0 = *(const bf16x8*)(pb + kb * 512);
    const bf16x8 b1 = *(const bf16x8*)(pb + 8192 + kb * 512);
    acc[0] = __builtin_amdgcn_mfma_f32_32x32x16_bf16(a, b0, acc[0], 0, 0, 0);
    acc[1] = __builtin_amdgcn_mfma_f32_32x32x16_bf16(a, b1, acc[1], 0, 0, 0);
  }
#pragma unroll
  for (int nt = 0; nt < 2; ++nt) {
#pragma unroll
    for (int q = 0; q < 4; ++q)
#pragma unroll
      for (int rr = 0; rr < 4; ++rr) {
        const int row = m0 + rr + 8 * q + 4 * half;
        const int cc = n0 + nt * 32 + col;
        C[(size_t)row * 1024 + cc] = acc[nt][q * 4 + rr] + bias[row];
      }
  }
}

extern "C" void kernel_launch(void* const* d_in, const int* in_sizes, int n_in,
                              void* d_out, int out_size, void* d_ws, size_t ws_size,
                              hipStream_t stream) {
  const float* x     = (const float*)d_in[0];
  const float* fc_w  = (const float*)d_in[1];
  const float* fc_b  = (const float*)d_in[2];
  const float* gamma = (const float*)d_in[3];
  const float* beta  = (const float*)d_in[4];
  const float* dw    = (const float*)d_in[5];
  const float* db    = (const float*)d_in[6];
  const float* ow    = (const float*)d_in[7];
  const float* ob    = (const float*)d_in[8];

  float* ws   = (float*)d_ws;
  short* xp   = (short*)(ws + OFF_XP);
  float* convp= ws + OFF_XP;              // aliases xp (dead after gram2+fc2)
  short* xr   = (short*)(ws + OFF_XR);
  short* vb   = (short*)(ws + OFF_VB);
  short* tbs  = (short*)(ws + OFF_TBS);
  short* xdtb = (short*)(ws + OFF_TBS);   // aliases tbs (dead after hgemm_t2)
  short* tbs2 = (short*)(ws + OFF_TBS2);
  short* xpp  = (short*)(ws + OFF_TBS2);  // aliases tbs2 (dead after hgemm_n2)
  unsigned* hg = (unsigned*)(ws + OFF_HG);
  float* sqv  = ws + OFF_SQ;
  float* part = ws + OFF_PART;
  float* bnss = ws + OFF_BNSS;
  float* dinvf= ws + OFF_DINV;
  short* w3p  = (short*)(ws + OFF_W3P);
  short* wfcp = (short*)(ws + OFF_WFCP);
  short* woutp= (short*)(ws + OFF_WOUTP);
  float* out  = (float*)d_out;

  k_transpose<<<dim3(128, 8, 2), dim3(32, 8), 0, stream>>>(x, xp, xr);
  k_sqx<<<dim3(64, 2), 256, 0, stream>>>(x, sqv);
  k_packall<<<3072, 256, 0, stream>>>(fc_w, ow, dw, wfcp, woutp, w3p);
  k_gram2<<<dim3(32, 32, 2), 256, 0, stream>>>(xp, sqv, hg);
  // yT (swizzled bf16) = fc_w @ xf^T + fc_b
  k_mfma_fc2<<<dim3(64, 2, 2), 256, 0, stream>>>(wfcp, xp, tbs, fc_b);
  k_dinv<<<8192, 64, 0, stream>>>(hg, dinvf);
  // E^T (swizzled bf16) = (y^T . H^T) * dinv[n]
  k_hgemm_t2<<<dim3(128, 4, 2), 64, 0, stream>>>(tbs, hg, dinvf, tbs2);
  // v (bf16 row-major) = (H . E) * dinv[i] + xf
  k_hgemm_n2<<<dim3(4, 128, 2), 64, 0, stream>>>(hg, tbs2, dinvf, xr, vb);
  // BN + SiLU -> conv input pack
  k_bnstat<<<128, 256, 0, stream>>>(vb, part);
  k_bnfin<<<1, 256, 0, stream>>>(part, gamma, beta, bnss);
  k_bnapply3<<<2048, 256, 0, stream>>>(vb, bnss, xpp);
  // 3x3 s2 conv (packed MFMA, K split 2-way) -> f32 partials -> packed bf16
  k_conv4<<<dim3(8, 32, 4), 64, 0, stream>>>(xpp, w3p, convp);
  k_convmerge2<<<512, 256, 0, stream>>>(convp, db, xdtb);
  // out = out_w @ xdT^T + out_b
  k_mfma_nt2<<<dim3(16, 4, 2), 256, 0, stream>>>(woutp, xdtb, out, ob);
}